// Round 1
// 1479.877 us; speedup vs baseline: 1.2049x; 1.2049x over previous
//
#include <hip/hip_runtime.h>
#include <math.h>

#define B_ 4
#define S_ 1024
#define D_ 1024
#define F_ 2048
#define H_ 16
#define E_ 8
#define DK_ 64
#define NTOK (B_*S_)

typedef unsigned short ushort_t;
typedef __attribute__((ext_vector_type(8))) short short8;
typedef __attribute__((ext_vector_type(4))) float floatx4;

// ---- bf16 helpers (RNE) ----
__device__ __forceinline__ ushort_t f2bf(float f) {
    unsigned u = __float_as_uint(f);
    unsigned r = (u + 0x7fffu + ((u >> 16) & 1u)) >> 16;
    return (ushort_t)r;
}
__device__ __forceinline__ float bf2f(ushort_t h) {
    return __uint_as_float(((unsigned)h) << 16);
}

// ---- async global->LDS 16B ----
__device__ __forceinline__ void gload16(const void* g, void* l) {
    __builtin_amdgcn_global_load_lds(
        (const __attribute__((address_space(1))) unsigned*)g,
        (__attribute__((address_space(3))) unsigned*)l, 16, 0, 0);
}

// ---------------- block reductions (256 threads = 4 waves) ----------------
__device__ __forceinline__ float blockReduceSum256(float v, volatile float* sred) {
    int tid = threadIdx.x;
    #pragma unroll
    for (int o = 32; o > 0; o >>= 1) v += __shfl_down(v, o, 64);
    __syncthreads();
    if ((tid & 63) == 0) sred[tid >> 6] = v;
    __syncthreads();
    return sred[0] + sred[1] + sred[2] + sred[3];
}

// ---------------- LayerNorm: one block per row; writes f32 (opt) + bf16 ----
__global__ __launch_bounds__(256)
void ln_kernel(const float* __restrict__ x, const float* __restrict__ g,
               const float* __restrict__ b, float* __restrict__ yf,
               ushort_t* __restrict__ yh) {
    __shared__ float sred[4];
    int row = blockIdx.x;
    int tid = threadIdx.x;
    const float* xr = x + (size_t)row * D_;
    float v[4];
    float s = 0.f;
    #pragma unroll
    for (int i = 0; i < 4; i++) { v[i] = xr[tid + 256*i]; s += v[i]; }
    float mean = blockReduceSum256(s, sred) * (1.f / D_);
    float s2 = 0.f;
    #pragma unroll
    for (int i = 0; i < 4; i++) { float d = v[i] - mean; s2 += d * d; }
    float var = blockReduceSum256(s2, sred) * (1.f / D_);
    float rstd = rsqrtf(var + 1e-5f);
    #pragma unroll
    for (int i = 0; i < 4; i++) {
        int c = tid + 256*i;
        float r = (v[i] - mean) * rstd * g[c] + b[c];
        if (yf) yf[(size_t)row * D_ + c] = r;
        yh[(size_t)row * D_ + c] = f2bf(r);
    }
}

// ---------------- transpose+convert: src[R,C] f32 -> dst[C,R] bf16 --------
__global__ __launch_bounds__(256)
void transpose_cvt(const float* __restrict__ s1, ushort_t* __restrict__ d1,
                   const float* __restrict__ s2, ushort_t* __restrict__ d2,
                   int R, int C)
{
    const float* s = blockIdx.z ? s2 : s1;
    ushort_t* d = blockIdx.z ? d2 : d1;
    __shared__ float t[32][33];
    int r0 = blockIdx.y * 32, c0 = blockIdx.x * 32;
    int lr = threadIdx.x >> 3, lc = (threadIdx.x & 7) * 4;
    float4 v = *(const float4*)(s + (size_t)(r0 + lr) * C + c0 + lc);
    t[lr][lc+0] = v.x; t[lr][lc+1] = v.y; t[lr][lc+2] = v.z; t[lr][lc+3] = v.w;
    __syncthreads();
    ushort4 o;
    o.x = f2bf(t[lc+0][lr]); o.y = f2bf(t[lc+1][lr]);
    o.z = f2bf(t[lc+2][lr]); o.w = f2bf(t[lc+3][lr]);
    *(ushort4*)(d + (size_t)(c0 + lr) * R + r0 + lc) = o;
}

struct W7 { const float* s[7]; ushort_t* d[7]; };
__global__ __launch_bounds__(256)
void transpose7(W7 p, int R, int C)
{
    const float* s = p.s[blockIdx.z];
    ushort_t* d = p.d[blockIdx.z];
    __shared__ float t[32][33];
    int r0 = blockIdx.y * 32, c0 = blockIdx.x * 32;
    int lr = threadIdx.x >> 3, lc = (threadIdx.x & 7) * 4;
    float4 v = *(const float4*)(s + (size_t)(r0 + lr) * C + c0 + lc);
    t[lr][lc+0] = v.x; t[lr][lc+1] = v.y; t[lr][lc+2] = v.z; t[lr][lc+3] = v.w;
    __syncthreads();
    ushort4 o;
    o.x = f2bf(t[lc+0][lr]); o.y = f2bf(t[lc+1][lr]);
    o.z = f2bf(t[lc+2][lr]); o.w = f2bf(t[lc+3][lr]);
    *(ushort4*)(d + (size_t)(c0 + lr) * R + r0 + lc) = o;
}

// ---------------- MFMA bf16 GEMM: C = A[M,K] @ B^T (B stored [N,K]) ------
// 128x128 tile, BK=32, 256 thr (2x2 waves of 64x64), 16x16x32 MFMA.
// MODE 1: Cf = acc + bias1 + R                (f32 out)
// MODE 3: Ch = silu(acc1+bias1)*(acc2+bias2)  (bf16 out, dual B)
template<int MODE>
__global__ __launch_bounds__(256)
void mgemm(const ushort_t* __restrict__ A, const ushort_t* __restrict__ B1,
           const float* __restrict__ bias1, const ushort_t* __restrict__ B2,
           const float* __restrict__ bias2, const float* __restrict__ R,
           void* __restrict__ Cv, int M, int N, int K)
{
    __shared__ __align__(16) ushort_t As [128*32];
    __shared__ __align__(16) ushort_t Bs1[128*32];
    __shared__ __align__(16) ushort_t Bs2[(MODE == 3) ? 128*32 : 16];

    int tid = threadIdx.x;
    int m0 = blockIdx.y * 128, n0 = blockIdx.x * 128;
    int trow = tid >> 2;             // 0..63
    int tcol = (tid & 3) * 8;        // k-element offset (16B chunks)
    const ushort_t* gA  = A  + (size_t)(m0 + trow) * K + tcol;
    const ushort_t* gB1 = B1 + (size_t)(n0 + trow) * K + tcol;
    const ushort_t* gB2 = (MODE == 3) ? B2 + (size_t)(n0 + trow) * K + tcol : nullptr;
    ushort_t* lA  = &As [trow*32 + tcol];
    ushort_t* lB1 = &Bs1[trow*32 + tcol];
    ushort_t* lB2 = (MODE == 3) ? &Bs2[trow*32 + tcol] : nullptr;

    int wave = tid >> 6, lane = tid & 63;
    int wm = (wave >> 1) * 64, wn = (wave & 1) * 64;
    int fr = lane & 15, fk = (lane >> 4) * 8;
    const ushort_t* pa  = &As [(wm + fr)*32 + fk];
    const ushort_t* pb1 = &Bs1[(wn + fr)*32 + fk];
    const ushort_t* pb2 = (MODE == 3) ? &Bs2[(wn + fr)*32 + fk] : nullptr;

    floatx4 acc1[4][4];
    floatx4 acc2[(MODE == 3) ? 4 : 1][(MODE == 3) ? 4 : 1];
    #pragma unroll
    for (int i = 0; i < 4; i++)
        #pragma unroll
        for (int j = 0; j < 4; j++) {
            acc1[i][j] = (floatx4)(0.f);
            if (MODE == 3) acc2[i][j] = (floatx4)(0.f);
        }

    for (int k0 = 0; k0 < K; k0 += 32) {
        gload16(gA  + k0,            lA);
        gload16(gA  + (size_t)64*K + k0, lA  + 64*32);
        gload16(gB1 + k0,            lB1);
        gload16(gB1 + (size_t)64*K + k0, lB1 + 64*32);
        if (MODE == 3) {
            gload16(gB2 + k0,            lB2);
            gload16(gB2 + (size_t)64*K + k0, lB2 + 64*32);
        }
        __syncthreads();

        short8 a[4];
        #pragma unroll
        for (int mt = 0; mt < 4; mt++) a[mt] = *(const short8*)(pa + mt*16*32);
        {
            short8 b[4];
            #pragma unroll
            for (int nt = 0; nt < 4; nt++) b[nt] = *(const short8*)(pb1 + nt*16*32);
            #pragma unroll
            for (int mt = 0; mt < 4; mt++)
                #pragma unroll
                for (int nt = 0; nt < 4; nt++)
                    acc1[mt][nt] = __builtin_amdgcn_mfma_f32_16x16x32_bf16(
                        a[mt], b[nt], acc1[mt][nt], 0, 0, 0);
        }
        if (MODE == 3) {
            short8 b[4];
            #pragma unroll
            for (int nt = 0; nt < 4; nt++) b[nt] = *(const short8*)(pb2 + nt*16*32);
            #pragma unroll
            for (int mt = 0; mt < 4; mt++)
                #pragma unroll
                for (int nt = 0; nt < 4; nt++)
                    acc2[mt][nt] = __builtin_amdgcn_mfma_f32_16x16x32_bf16(
                        a[mt], b[nt], acc2[mt][nt], 0, 0, 0);
        }
        __syncthreads();
    }

    int ecol0 = n0 + wn + (lane & 15);
    int erow0 = m0 + wm + (lane >> 4) * 4;
    #pragma unroll
    for (int mt = 0; mt < 4; mt++) {
        #pragma unroll
        for (int nt = 0; nt < 4; nt++) {
            int col = ecol0 + nt * 16;
            #pragma unroll
            for (int r = 0; r < 4; r++) {
                int row = erow0 + mt * 16 + r;
                size_t idx = (size_t)row * N + col;
                if (MODE == 3) {
                    float x1 = acc1[mt][nt][r] + bias1[col];
                    float x2 = acc2[mt][nt][r] + bias2[col];
                    float h = x1 / (1.f + __expf(-x1)) * x2;
                    ((ushort_t*)Cv)[idx] = f2bf(h);
                } else {
                    ((float*)Cv)[idx] = acc1[mt][nt][r] + bias1[col] + R[idx];
                }
            }
        }
    }
}

// ------- sparse MoE up-proj: rows gathered via idx list, dual-B SwiGLU -----
// A = x2 bf16 [NTOK,K]; C compact [row,N] bf16. Grid y covers NTOK/128 tiles.
__global__ __launch_bounds__(256)
void mgemm_up(const ushort_t* __restrict__ A, const int* __restrict__ idxl,
              const int* __restrict__ counts, int e,
              const ushort_t* __restrict__ B1, const float* __restrict__ bias1,
              const ushort_t* __restrict__ B2, const float* __restrict__ bias2,
              ushort_t* __restrict__ C, int N, int K)
{
    int cnt = counts[e];
    int m0 = blockIdx.y * 128;
    if (m0 >= cnt) return;

    __shared__ __align__(16) ushort_t As [128*32];
    __shared__ __align__(16) ushort_t Bs1[128*32];
    __shared__ __align__(16) ushort_t Bs2[128*32];

    int tid = threadIdx.x;
    int n0 = blockIdx.x * 128;
    int trow = tid >> 2;
    int tcol = (tid & 3) * 8;
    int r0 = m0 + trow, r1 = m0 + 64 + trow;
    int t0 = (r0 < cnt) ? idxl[r0] : 0;
    int t1 = (r1 < cnt) ? idxl[r1] : 0;
    const ushort_t* gA0 = A + (size_t)t0 * K + tcol;
    const ushort_t* gA1 = A + (size_t)t1 * K + tcol;
    const ushort_t* gB1 = B1 + (size_t)(n0 + trow) * K + tcol;
    const ushort_t* gB2 = B2 + (size_t)(n0 + trow) * K + tcol;
    ushort_t* lA  = &As [trow*32 + tcol];
    ushort_t* lB1 = &Bs1[trow*32 + tcol];
    ushort_t* lB2 = &Bs2[trow*32 + tcol];

    int wave = tid >> 6, lane = tid & 63;
    int wm = (wave >> 1) * 64, wn = (wave & 1) * 64;
    int fr = lane & 15, fk = (lane >> 4) * 8;
    const ushort_t* pa  = &As [(wm + fr)*32 + fk];
    const ushort_t* pb1 = &Bs1[(wn + fr)*32 + fk];
    const ushort_t* pb2 = &Bs2[(wn + fr)*32 + fk];

    floatx4 acc1[4][4], acc2[4][4];
    #pragma unroll
    for (int i = 0; i < 4; i++)
        #pragma unroll
        for (int j = 0; j < 4; j++) { acc1[i][j] = (floatx4)(0.f); acc2[i][j] = (floatx4)(0.f); }

    for (int k0 = 0; k0 < K; k0 += 32) {
        gload16(gA0 + k0, lA);
        gload16(gA1 + k0, lA + 64*32);
        gload16(gB1 + k0, lB1);
        gload16(gB1 + (size_t)64*K + k0, lB1 + 64*32);
        gload16(gB2 + k0, lB2);
        gload16(gB2 + (size_t)64*K + k0, lB2 + 64*32);
        __syncthreads();

        short8 a[4];
        #pragma unroll
        for (int mt = 0; mt < 4; mt++) a[mt] = *(const short8*)(pa + mt*16*32);
        {
            short8 b[4];
            #pragma unroll
            for (int nt = 0; nt < 4; nt++) b[nt] = *(const short8*)(pb1 + nt*16*32);
            #pragma unroll
            for (int mt = 0; mt < 4; mt++)
                #pragma unroll
                for (int nt = 0; nt < 4; nt++)
                    acc1[mt][nt] = __builtin_amdgcn_mfma_f32_16x16x32_bf16(
                        a[mt], b[nt], acc1[mt][nt], 0, 0, 0);
        }
        {
            short8 b[4];
            #pragma unroll
            for (int nt = 0; nt < 4; nt++) b[nt] = *(const short8*)(pb2 + nt*16*32);
            #pragma unroll
            for (int mt = 0; mt < 4; mt++)
                #pragma unroll
                for (int nt = 0; nt < 4; nt++)
                    acc2[mt][nt] = __builtin_amdgcn_mfma_f32_16x16x32_bf16(
                        a[mt], b[nt], acc2[mt][nt], 0, 0, 0);
        }
        __syncthreads();
    }

    int ecol0 = n0 + wn + (lane & 15);
    int erow0 = m0 + wm + (lane >> 4) * 4;
    #pragma unroll
    for (int mt = 0; mt < 4; mt++) {
        #pragma unroll
        for (int nt = 0; nt < 4; nt++) {
            int col = ecol0 + nt * 16;
            #pragma unroll
            for (int r = 0; r < 4; r++) {
                int row = erow0 + mt * 16 + r;
                float x1 = acc1[mt][nt][r] + bias1[col];
                float x2 = acc2[mt][nt][r] + bias2[col];
                float h = x1 / (1.f + __expf(-x1)) * x2;
                C[(size_t)row * N + col] = f2bf(h);
            }
        }
    }
}

// ------- sparse MoE down-proj: A compact [row,K]; scatter out[token] += w*row
__global__ __launch_bounds__(256)
void mgemm_down(const ushort_t* __restrict__ A, const int* __restrict__ idxl,
                const float* __restrict__ wgtl, const int* __restrict__ counts, int e,
                const ushort_t* __restrict__ B1, const float* __restrict__ bias1,
                float* __restrict__ out, int N, int K)
{
    int cnt = counts[e];
    int m0 = blockIdx.y * 128;
    if (m0 >= cnt) return;

    __shared__ __align__(16) ushort_t As [128*32];
    __shared__ __align__(16) ushort_t Bs1[128*32];

    int tid = threadIdx.x;
    int n0 = blockIdx.x * 128;
    int trow = tid >> 2;
    int tcol = (tid & 3) * 8;
    const ushort_t* gA  = A  + (size_t)(m0 + trow) * K + tcol;
    const ushort_t* gB1 = B1 + (size_t)(n0 + trow) * K + tcol;
    ushort_t* lA  = &As [trow*32 + tcol];
    ushort_t* lB1 = &Bs1[trow*32 + tcol];

    int wave = tid >> 6, lane = tid & 63;
    int wm = (wave >> 1) * 64, wn = (wave & 1) * 64;
    int fr = lane & 15, fk = (lane >> 4) * 8;
    const ushort_t* pa  = &As [(wm + fr)*32 + fk];
    const ushort_t* pb1 = &Bs1[(wn + fr)*32 + fk];

    floatx4 acc1[4][4];
    #pragma unroll
    for (int i = 0; i < 4; i++)
        #pragma unroll
        for (int j = 0; j < 4; j++) acc1[i][j] = (floatx4)(0.f);

    for (int k0 = 0; k0 < K; k0 += 32) {
        gload16(gA + k0,             lA);
        gload16(gA + (size_t)64*K + k0, lA + 64*32);
        gload16(gB1 + k0,            lB1);
        gload16(gB1 + (size_t)64*K + k0, lB1 + 64*32);
        __syncthreads();

        short8 a[4];
        #pragma unroll
        for (int mt = 0; mt < 4; mt++) a[mt] = *(const short8*)(pa + mt*16*32);
        short8 b[4];
        #pragma unroll
        for (int nt = 0; nt < 4; nt++) b[nt] = *(const short8*)(pb1 + nt*16*32);
        #pragma unroll
        for (int mt = 0; mt < 4; mt++)
            #pragma unroll
            for (int nt = 0; nt < 4; nt++)
                acc1[mt][nt] = __builtin_amdgcn_mfma_f32_16x16x32_bf16(
                    a[mt], b[nt], acc1[mt][nt], 0, 0, 0);
        __syncthreads();
    }

    int ecol0 = n0 + wn + (lane & 15);
    int erow0 = m0 + wm + (lane >> 4) * 4;
    #pragma unroll
    for (int mt = 0; mt < 4; mt++) {
        int rowb = erow0 + mt * 16;
        int tok[4]; float wv[4];
        #pragma unroll
        for (int r = 0; r < 4; r++) {
            int row = rowb + r;
            tok[r] = (row < cnt) ? idxl[row] : -1;
            wv[r]  = (row < cnt) ? wgtl[row] : 0.f;
        }
        #pragma unroll
        for (int nt = 0; nt < 4; nt++) {
            int col = ecol0 + nt * 16;
            #pragma unroll
            for (int r = 0; r < 4; r++) {
                if (tok[r] >= 0)
                    out[(size_t)tok[r] * N + col] += wv[r] * (acc1[mt][nt][r] + bias1[col]);
            }
        }
    }
}

// ---------------- MFMA flash attention (bf16 in/out, f32 accum) -----------
// Grid: B*H*(S/64) blocks, 256 threads = 4 waves. Wave w owns q rows
// s0+w*16 .. s0+w*16+15, Q held in registers (2 A-frags of 16x16x32).
// Per 64-wide K/V tile: K staged [64][72] row-major (72-pad => 144B rows,
// bank quad rotates by 4/row -> balanced b128 reads, no swizzle needed);
// V staged transposed [d][k] in [64][72] (transpose on global-read side:
// lane reads column d=lane via coalesced 128B wave transactions).
// Softmax online in registers; P -> per-wave LDS region (bf16) to reshape
// into A-fragment layout for the PV MFMA.
__global__ __launch_bounds__(256)
void fattn_kernel(const ushort_t* __restrict__ q, const ushort_t* __restrict__ k,
                  const ushort_t* __restrict__ v, ushort_t* __restrict__ ctx)
{
    __shared__ __align__(16) ushort_t Ks[64*72];     // [k][d] padded
    __shared__ __align__(16) ushort_t Vt[64*72];     // [d][k] padded
    __shared__ __align__(16) ushort_t Ps[4][16*72];  // per-wave P [q][k]

    const int bid = blockIdx.x;
    const int qt = bid & (S_/64 - 1);
    const int h  = (bid >> 4) & (H_ - 1);
    const int b  = bid >> 8;
    const int tid = threadIdx.x;
    const int wave = tid >> 6, lane = tid & 63;
    const int RS = H_ * DK_;                         // token stride (elems)
    const size_t headbase = ((size_t)b * S_ * H_ + h) * DK_;
    const int s0 = qt * 64;
    const int lr = lane & 15, lg = lane >> 4;

    // Q fragments in registers: A row = lane&15, k = (lane>>4)*8 + half*32
    short8 qf0, qf1;
    {
        const ushort_t* qp = q + headbase + (size_t)(s0 + wave*16 + lr) * RS + lg * 8;
        qf0 = *(const short8*)qp;
        qf1 = *(const short8*)(qp + 32);
    }

    floatx4 O[4];
    float m_i[4], l_i[4];
    #pragma unroll
    for (int i = 0; i < 4; i++) { O[i] = (floatx4)(0.f); m_i[i] = -1e30f; l_i[i] = 0.f; }

    const int kr = tid >> 3, kc = (tid & 7) * 8;     // K staging assignment
    ushort_t* pw = Ps[wave];

    for (int t = 0; t < S_/64; t++) {
        const int kbase = t * 64;
        __syncthreads();                              // prev-iter reads done
        // ---- stage K tile [64][72], coalesced b128 global reads ----
        {
            const ushort_t* kp = k + headbase + (size_t)(kbase + kr) * RS + kc;
            short8 k0 = *(const short8*)kp;
            short8 k1 = *(const short8*)(kp + (size_t)32 * RS);
            *(short8*)&Ks[kr*72 + kc]        = k0;
            *(short8*)&Ks[(kr + 32)*72 + kc] = k1;
        }
        // ---- stage V^T: lane reads column d=lane (128B coalesced per j) ----
        {
            const ushort_t* vp = v + headbase + (size_t)(kbase + wave*16) * RS + lane;
            short8 w0, w1;
            #pragma unroll
            for (int j = 0; j < 8; j++) {
                ((ushort_t*)&w0)[j] = vp[(size_t)j * RS];
                ((ushort_t*)&w1)[j] = vp[(size_t)(j + 8) * RS];
            }
            *(short8*)&Vt[lane*72 + wave*16]     = w0;
            *(short8*)&Vt[lane*72 + wave*16 + 8] = w1;
        }
        __syncthreads();

        // ---- S = (Q K^T) * 0.125 ; S[q=(lg*4+r)][kcol=lr+16*nt] ----
        floatx4 sacc[4];
        #pragma unroll
        for (int nt = 0; nt < 4; nt++) sacc[nt] = (floatx4)(0.f);
        #pragma unroll
        for (int nt = 0; nt < 4; nt++) {
            short8 b0 = *(const short8*)&Ks[(lr + nt*16)*72 + lg*8];
            sacc[nt] = __builtin_amdgcn_mfma_f32_16x16x32_bf16(qf0, b0, sacc[nt], 0, 0, 0);
            short8 b1 = *(const short8*)&Ks[(lr + nt*16)*72 + 32 + lg*8];
            sacc[nt] = __builtin_amdgcn_mfma_f32_16x16x32_bf16(qf1, b1, sacc[nt], 0, 0, 0);
        }

        // ---- online softmax: row reduce across the 16-lane column group ----
        float alpha[4];
        #pragma unroll
        for (int r = 0; r < 4; r++) {
            float rm = -1e30f;
            #pragma unroll
            for (int nt = 0; nt < 4; nt++) { sacc[nt][r] *= 0.125f; rm = fmaxf(rm, sacc[nt][r]); }
            #pragma unroll
            for (int o = 1; o < 16; o <<= 1) rm = fmaxf(rm, __shfl_xor(rm, o, 64));
            float nm = fmaxf(m_i[r], rm);
            alpha[r] = __expf(m_i[r] - nm);
            m_i[r] = nm;
            float rs = 0.f;
            #pragma unroll
            for (int nt = 0; nt < 4; nt++) { sacc[nt][r] = __expf(sacc[nt][r] - nm); rs += sacc[nt][r]; }
            #pragma unroll
            for (int o = 1; o < 16; o <<= 1) rs += __shfl_xor(rs, o, 64);
            l_i[r] = l_i[r] * alpha[r] + rs;
        }

        // ---- P -> per-wave LDS (bf16), reshaping for A-fragment reads ----
        #pragma unroll
        for (int nt = 0; nt < 4; nt++)
            #pragma unroll
            for (int r = 0; r < 4; r++)
                pw[(lg*4 + r)*72 + lr + nt*16] = f2bf(sacc[nt][r]);

        // ---- O rescale, then O += P V ----
        #pragma unroll
        for (int nt = 0; nt < 4; nt++)
            #pragma unroll
            for (int r = 0; r < 4; r++)
                O[nt][r] *= alpha[r];

        asm volatile("s_waitcnt lgkmcnt(0)" ::: "memory");  // P writes visible (same wave)

        #pragma unroll
        for (int kh = 0; kh < 2; kh++) {
            short8 pa = *(const short8*)&pw[lr*72 + kh*32 + lg*8];
            #pragma unroll
            for (int nt = 0; nt < 4; nt++) {
                short8 bv = *(const short8*)&Vt[(lr + nt*16)*72 + kh*32 + lg*8];
                O[nt] = __builtin_amdgcn_mfma_f32_16x16x32_bf16(pa, bv, O[nt], 0, 0, 0);
            }
        }
    }

    // ---- epilogue: O/l via per-wave LDS transpose for coalesced stores ----
    #pragma unroll
    for (int r = 0; r < 4; r++) {
        float inv = 1.f / l_i[r];
        #pragma unroll
        for (int nt = 0; nt < 4; nt++)
            pw[(lg*4 + r)*72 + lr + nt*16] = f2bf(O[nt][r] * inv);
    }
    asm volatile("s_waitcnt lgkmcnt(0)" ::: "memory");
    {
        const int row = lane >> 2, c0 = (lane & 3) * 16;
        short8 o0 = *(const short8*)&pw[row*72 + c0];
        short8 o1 = *(const short8*)&pw[row*72 + c0 + 8];
        ushort_t* gp = ctx + headbase + (size_t)(s0 + wave*16 + row) * RS + c0;
        *(short8*)gp       = o0;
        *(short8*)(gp + 8) = o1;
    }
}

// ---------------- gate: one wave per token -> append to expert lists ------
__global__ __launch_bounds__(64)
void gate_kernel(const float* __restrict__ x2, const float* __restrict__ gw,
                 const float* __restrict__ gb, int* __restrict__ counts,
                 int* __restrict__ idxl, float* __restrict__ wgtl)
{
    int row = blockIdx.x;
    int lane = threadIdx.x;
    const float* xr = x2 + (size_t)row * D_;
    float p[E_] = {0.f};
    for (int dd = lane; dd < D_; dd += 64) {
        float xv = xr[dd];
        const float* g = gw + (size_t)dd * E_;
        #pragma unroll
        for (int e = 0; e < E_; e++) p[e] += xv * g[e];
    }
    #pragma unroll
    for (int e = 0; e < E_; e++)
        #pragma unroll
        for (int o = 32; o > 0; o >>= 1) p[e] += __shfl_down(p[e], o, 64);
    if (lane == 0) {
        float mx = -1e30f;
        #pragma unroll
        for (int e = 0; e < E_; e++) { p[e] += gb[e]; mx = fmaxf(mx, p[e]); }
        float sum = 0.f;
        #pragma unroll
        for (int e = 0; e < E_; e++) { p[e] = expf(p[e] - mx); sum += p[e]; }
        #pragma unroll
        for (int e = 0; e < E_; e++) p[e] /= sum;
        int i1 = 0;
        #pragma unroll
        for (int e = 1; e < E_; e++) if (p[e] > p[i1]) i1 = e;
        int i2 = (i1 == 0) ? 1 : 0;
        #pragma unroll
        for (int e = 0; e < E_; e++) if (e != i2 && e != i1 && p[e] > p[i2]) i2 = e;
        float denom = p[i1] + p[i2] + 1e-6f;
        int pos1 = atomicAdd(&counts[i1], 1);
        idxl[(size_t)i1 * NTOK + pos1] = row;
        wgtl[(size_t)i1 * NTOK + pos1] = p[i1] / denom;
        int pos2 = atomicAdd(&counts[i2], 1);
        idxl[(size_t)i2 * NTOK + pos2] = row;
        wgtl[(size_t)i2 * NTOK + pos2] = p[i2] / denom;
    }
}

extern "C" void kernel_launch(void* const* d_in, const int* in_sizes, int n_in,
                              void* d_out, int out_size, void* d_ws, size_t ws_size,
                              hipStream_t stream)
{
    const float* x    = (const float*)d_in[0];
    const float* wq1  = (const float*)d_in[2];
    const float* bq1  = (const float*)d_in[3];
    const float* wq2  = (const float*)d_in[4];
    const float* bq2  = (const float*)d_in[5];
    const float* wk1  = (const float*)d_in[6];
    const float* bk1  = (const float*)d_in[7];
    const float* wk2  = (const float*)d_in[8];
    const float* bk2  = (const float*)d_in[9];
    const float* wv1  = (const float*)d_in[10];
    const float* bv1  = (const float*)d_in[11];
    const float* wv2  = (const float*)d_in[12];
    const float* bv2  = (const float*)d_in[13];
    const float* wo   = (const float*)d_in[14];
    const float* bo   = (const float*)d_in[15];
    const float* ln1g = (const float*)d_in[16];
    const float* ln1b = (const float*)d_in[17];
    const float* ln2g = (const float*)d_in[18];
    const float* ln2b = (const float*)d_in[19];
    const float* gw   = (const float*)d_in[20];
    const float* gb   = (const float*)d_in[21];
    const float* ew1  = (const float*)d_in[22];
    const float* eb1  = (const float*)d_in[23];
    const float* ew2  = (const float*)d_in[24];
    const float* eb2  = (const float*)d_in[25];
    const float* ew3  = (const float*)d_in[26];
    const float* eb3  = (const float*)d_in[27];
    float* out = (float*)d_out;

    char* w = (char*)d_ws;
    ushort_t* wq1t = (ushort_t*)w; w += (size_t)D_*D_*2;
    ushort_t* wq2t = (ushort_t*)w; w += (size_t)D_*D_*2;
    ushort_t* wk1t = (ushort_t*)w; w += (size_t)D_*D_*2;
    ushort_t* wk2t = (ushort_t*)w; w += (size_t)D_*D_*2;
    ushort_t* wv1t = (ushort_t*)w; w += (size_t)D_*D_*2;
    ushort_t* wv2t = (ushort_t*)w; w += (size_t)D_*D_*2;
    ushort_t* wot  = (ushort_t*)w; w += (size_t)D_*D_*2;
    ushort_t* e1t  = (ushort_t*)w; w += (size_t)D_*F_*2;
    ushort_t* e3t  = (ushort_t*)w; w += (size_t)D_*F_*2;
    ushort_t* e2t  = (ushort_t*)w; w += (size_t)D_*F_*2;
    ushort_t* x2h  = (ushort_t*)w; w += (size_t)NTOK*D_*2;
    ushort_t* qh   = (ushort_t*)w; w += (size_t)NTOK*D_*2;
    ushort_t* kh   = (ushort_t*)w; w += (size_t)NTOK*D_*2;
    ushort_t* vh   = (ushort_t*)w; w += (size_t)NTOK*D_*2;
    ushort_t* ctxh = (ushort_t*)w; w += (size_t)NTOK*D_*2;
    ushort_t* x2bh = (ushort_t*)w; w += (size_t)NTOK*D_*2;
    ushort_t* hAh  = (ushort_t*)w; w += (size_t)NTOK*F_*2;
    float*    x2bf = (float*)w;    w += (size_t)NTOK*D_*4;
    int*      cnts = (int*)w;      w += 256;
    int*      idxl = (int*)w;      w += (size_t)E_*NTOK*4;
    float*    wgtl = (float*)w;    w += (size_t)E_*NTOK*4;

    dim3 blk(256);

    W7 p7;
    p7.s[0]=wq1; p7.d[0]=wq1t; p7.s[1]=wq2; p7.d[1]=wq2t;
    p7.s[2]=wk1; p7.d[2]=wk1t; p7.s[3]=wk2; p7.d[3]=wk2t;
    p7.s[4]=wv1; p7.d[4]=wv1t; p7.s[5]=wv2; p7.d[5]=wv2t;
    p7.s[6]=wo;  p7.d[6]=wot;
    transpose7<<<dim3(32,32,7), blk, 0, stream>>>(p7, D_, D_);

    // --- pre-norm attention ---
    ln_kernel<<<NTOK, blk, 0, stream>>>(x, ln1g, ln1b, nullptr, x2h);
    dim3 gDD(D_/128, NTOK/128);
    mgemm<3><<<gDD, blk, 0, stream>>>(x2h, wq1t, bq1, wq2t, bq2, nullptr, qh, NTOK, D_, D_);
    mgemm<3><<<gDD, blk, 0, stream>>>(x2h, wk1t, bk1, wk2t, bk2, nullptr, kh, NTOK, D_, D_);
    mgemm<3><<<gDD, blk, 0, stream>>>(x2h, wv1t, bv1, wv2t, bv2, nullptr, vh, NTOK, D_, D_);
    fattn_kernel<<<B_ * H_ * (S_/64), blk, 0, stream>>>(qh, kh, vh, ctxh);
    mgemm<1><<<gDD, blk, 0, stream>>>(ctxh, wot, bo, nullptr, nullptr, x, out, NTOK, D_, D_);

    // --- pre-norm MoE SwiGLU FFN (top-2 sparse) ---
    ln_kernel<<<NTOK, blk, 0, stream>>>(out, ln2g, ln2b, x2bf, x2bh);
    hipMemsetAsync(cnts, 0, 256, stream);
    gate_kernel<<<NTOK, dim3(64), 0, stream>>>(x2bf, gw, gb, cnts, idxl, wgtl);

    dim3 gFD(F_/128, NTOK/128);
    for (int e = 0; e < E_; e++) {
        transpose_cvt<<<dim3(F_/32, D_/32, 2), blk, 0, stream>>>(
            ew1 + (size_t)e*D_*F_, e1t, ew3 + (size_t)e*D_*F_, e3t, D_, F_);
        transpose_cvt<<<dim3(D_/32, F_/32, 1), blk, 0, stream>>>(
            ew2 + (size_t)e*F_*D_, e2t, nullptr, nullptr, F_, D_);
        mgemm_up<<<gFD, blk, 0, stream>>>(x2bh, idxl + (size_t)e*NTOK, cnts, e,
                                          e1t, eb1 + (size_t)e*F_, e3t, eb3 + (size_t)e*F_,
                                          hAh, F_, D_);
        mgemm_down<<<gDD, blk, 0, stream>>>(hAh, idxl + (size_t)e*NTOK, wgtl + (size_t)e*NTOK,
                                            cnts, e, e2t, eb2 + (size_t)e*D_, out, D_, F_);
    }
}

// Round 2
// 1461.089 us; speedup vs baseline: 1.2204x; 1.0129x over previous
//
#include <hip/hip_runtime.h>
#include <math.h>

#define B_ 4
#define S_ 1024
#define D_ 1024
#define F_ 2048
#define H_ 16
#define E_ 8
#define DK_ 64
#define NTOK (B_*S_)

typedef unsigned short ushort_t;
typedef __attribute__((ext_vector_type(8))) short short8;
typedef __attribute__((ext_vector_type(4))) float floatx4;

// ---- bf16 helpers (RNE) ----
__device__ __forceinline__ ushort_t f2bf(float f) {
    unsigned u = __float_as_uint(f);
    unsigned r = (u + 0x7fffu + ((u >> 16) & 1u)) >> 16;
    return (ushort_t)r;
}
__device__ __forceinline__ float bf2f(ushort_t h) {
    return __uint_as_float(((unsigned)h) << 16);
}

// ---- async global->LDS 16B ----
__device__ __forceinline__ void gload16(const void* g, void* l) {
    __builtin_amdgcn_global_load_lds(
        (const __attribute__((address_space(1))) unsigned*)g,
        (__attribute__((address_space(3))) unsigned*)l, 16, 0, 0);
}

// ---------------- block reductions (256 threads = 4 waves) ----------------
__device__ __forceinline__ float blockReduceSum256(float v, volatile float* sred) {
    int tid = threadIdx.x;
    #pragma unroll
    for (int o = 32; o > 0; o >>= 1) v += __shfl_down(v, o, 64);
    __syncthreads();
    if ((tid & 63) == 0) sred[tid >> 6] = v;
    __syncthreads();
    return sred[0] + sred[1] + sred[2] + sred[3];
}

// ---------------- LayerNorm: one block per row; writes bf16 ---------------
__global__ __launch_bounds__(256)
void ln_kernel(const float* __restrict__ x, const float* __restrict__ g,
               const float* __restrict__ b, ushort_t* __restrict__ yh) {
    __shared__ float sred[4];
    int row = blockIdx.x;
    int tid = threadIdx.x;
    const float* xr = x + (size_t)row * D_;
    float v[4];
    float s = 0.f;
    #pragma unroll
    for (int i = 0; i < 4; i++) { v[i] = xr[tid + 256*i]; s += v[i]; }
    float mean = blockReduceSum256(s, sred) * (1.f / D_);
    float s2 = 0.f;
    #pragma unroll
    for (int i = 0; i < 4; i++) { float d = v[i] - mean; s2 += d * d; }
    float var = blockReduceSum256(s2, sred) * (1.f / D_);
    float rstd = rsqrtf(var + 1e-5f);
    #pragma unroll
    for (int i = 0; i < 4; i++) {
        int c = tid + 256*i;
        float r = (v[i] - mean) * rstd * g[c] + b[c];
        yh[(size_t)row * D_ + c] = f2bf(r);
    }
}

// ------- LayerNorm fused with MoE gate (softmax + top-2 + append) ---------
// One block per token row. LN as above; each thread also accumulates its
// 4 columns' contribution to the 8 expert logits, packed shuffle reduce,
// thread 0 does softmax/top-2/atomic append to expert lists.
__global__ __launch_bounds__(256)
void ln_gate_kernel(const float* __restrict__ x, const float* __restrict__ g,
                    const float* __restrict__ b, ushort_t* __restrict__ yh,
                    const float* __restrict__ gw, const float* __restrict__ gb,
                    int* __restrict__ counts, int* __restrict__ idxl,
                    float* __restrict__ wgtl) {
    __shared__ float sred[4];
    __shared__ float sgate[4][E_];
    int row = blockIdx.x;
    int tid = threadIdx.x;
    const float* xr = x + (size_t)row * D_;
    float v[4];
    float s = 0.f;
    #pragma unroll
    for (int i = 0; i < 4; i++) { v[i] = xr[tid + 256*i]; s += v[i]; }
    float mean = blockReduceSum256(s, sred) * (1.f / D_);
    float s2 = 0.f;
    #pragma unroll
    for (int i = 0; i < 4; i++) { float d = v[i] - mean; s2 += d * d; }
    float var = blockReduceSum256(s2, sred) * (1.f / D_);
    float rstd = rsqrtf(var + 1e-5f);

    float p[E_];
    #pragma unroll
    for (int e = 0; e < E_; e++) p[e] = 0.f;
    #pragma unroll
    for (int i = 0; i < 4; i++) {
        int c = tid + 256*i;
        float r = (v[i] - mean) * rstd * g[c] + b[c];
        yh[(size_t)row * D_ + c] = f2bf(r);
        const float* gwr = gw + (size_t)c * E_;
        #pragma unroll
        for (int e = 0; e < E_; e++) p[e] += r * gwr[e];
    }
    // packed 8-logit wave reduce
    #pragma unroll
    for (int o = 32; o > 0; o >>= 1)
        #pragma unroll
        for (int e = 0; e < E_; e++) p[e] += __shfl_down(p[e], o, 64);
    __syncthreads();
    if ((tid & 63) == 0) {
        #pragma unroll
        for (int e = 0; e < E_; e++) sgate[tid >> 6][e] = p[e];
    }
    __syncthreads();
    if (tid == 0) {
        float q[E_];
        float mx = -1e30f;
        #pragma unroll
        for (int e = 0; e < E_; e++) {
            q[e] = sgate[0][e] + sgate[1][e] + sgate[2][e] + sgate[3][e] + gb[e];
            mx = fmaxf(mx, q[e]);
        }
        float sum = 0.f;
        #pragma unroll
        for (int e = 0; e < E_; e++) { q[e] = expf(q[e] - mx); sum += q[e]; }
        #pragma unroll
        for (int e = 0; e < E_; e++) q[e] /= sum;
        int i1 = 0;
        #pragma unroll
        for (int e = 1; e < E_; e++) if (q[e] > q[i1]) i1 = e;
        int i2 = (i1 == 0) ? 1 : 0;
        #pragma unroll
        for (int e = 0; e < E_; e++) if (e != i2 && e != i1 && q[e] > q[i2]) i2 = e;
        float denom = q[i1] + q[i2] + 1e-6f;
        int pos1 = atomicAdd(&counts[i1], 1);
        idxl[(size_t)i1 * NTOK + pos1] = row;
        wgtl[(size_t)i1 * NTOK + pos1] = q[i1] / denom;
        int pos2 = atomicAdd(&counts[i2], 1);
        idxl[(size_t)i2 * NTOK + pos2] = row;
        wgtl[(size_t)i2 * NTOK + pos2] = q[i2] / denom;
    }
}

// ---------------- transpose+convert: src[R,C] f32 -> dst[C,R] bf16 --------
__global__ __launch_bounds__(256)
void transpose_cvt(const float* __restrict__ s1, ushort_t* __restrict__ d1,
                   const float* __restrict__ s2, ushort_t* __restrict__ d2,
                   int R, int C)
{
    const float* s = blockIdx.z ? s2 : s1;
    ushort_t* d = blockIdx.z ? d2 : d1;
    __shared__ float t[32][33];
    int r0 = blockIdx.y * 32, c0 = blockIdx.x * 32;
    int lr = threadIdx.x >> 3, lc = (threadIdx.x & 7) * 4;
    float4 v = *(const float4*)(s + (size_t)(r0 + lr) * C + c0 + lc);
    t[lr][lc+0] = v.x; t[lr][lc+1] = v.y; t[lr][lc+2] = v.z; t[lr][lc+3] = v.w;
    __syncthreads();
    ushort4 o;
    o.x = f2bf(t[lc+0][lr]); o.y = f2bf(t[lc+1][lr]);
    o.z = f2bf(t[lc+2][lr]); o.w = f2bf(t[lc+3][lr]);
    *(ushort4*)(d + (size_t)(c0 + lr) * R + r0 + lc) = o;
}

struct W7 { const float* s[7]; ushort_t* d[7]; };
__global__ __launch_bounds__(256)
void transpose7(W7 p, int R, int C)
{
    const float* s = p.s[blockIdx.z];
    ushort_t* d = p.d[blockIdx.z];
    __shared__ float t[32][33];
    int r0 = blockIdx.y * 32, c0 = blockIdx.x * 32;
    int lr = threadIdx.x >> 3, lc = (threadIdx.x & 7) * 4;
    float4 v = *(const float4*)(s + (size_t)(r0 + lr) * C + c0 + lc);
    t[lr][lc+0] = v.x; t[lr][lc+1] = v.y; t[lr][lc+2] = v.z; t[lr][lc+3] = v.w;
    __syncthreads();
    ushort4 o;
    o.x = f2bf(t[lc+0][lr]); o.y = f2bf(t[lc+1][lr]);
    o.z = f2bf(t[lc+2][lr]); o.w = f2bf(t[lc+3][lr]);
    *(ushort4*)(d + (size_t)(c0 + lr) * R + r0 + lc) = o;
}

// ---------------- MFMA bf16 GEMM: C = A[M,K] @ B^T (B stored [N,K]) ------
// 128x128 tile, BK=32, 256 thr (2x2 waves of 64x64), 16x16x32 MFMA.
// MODE 1: Cf = acc + bias1 + R                (f32 out)
// MODE 3: Ch = silu(acc1+bias1)*(acc2+bias2)  (bf16 out, dual B)
template<int MODE>
__global__ __launch_bounds__(256)
void mgemm(const ushort_t* __restrict__ A, const ushort_t* __restrict__ B1,
           const float* __restrict__ bias1, const ushort_t* __restrict__ B2,
           const float* __restrict__ bias2, const float* __restrict__ R,
           void* __restrict__ Cv, int M, int N, int K)
{
    __shared__ __align__(16) ushort_t As [128*32];
    __shared__ __align__(16) ushort_t Bs1[128*32];
    __shared__ __align__(16) ushort_t Bs2[(MODE == 3) ? 128*32 : 16];

    int tid = threadIdx.x;
    int m0 = blockIdx.y * 128, n0 = blockIdx.x * 128;
    int trow = tid >> 2;             // 0..63
    int tcol = (tid & 3) * 8;        // k-element offset (16B chunks)
    const ushort_t* gA  = A  + (size_t)(m0 + trow) * K + tcol;
    const ushort_t* gB1 = B1 + (size_t)(n0 + trow) * K + tcol;
    const ushort_t* gB2 = (MODE == 3) ? B2 + (size_t)(n0 + trow) * K + tcol : nullptr;
    ushort_t* lA  = &As [trow*32 + tcol];
    ushort_t* lB1 = &Bs1[trow*32 + tcol];
    ushort_t* lB2 = (MODE == 3) ? &Bs2[trow*32 + tcol] : nullptr;

    int wave = tid >> 6, lane = tid & 63;
    int wm = (wave >> 1) * 64, wn = (wave & 1) * 64;
    int fr = lane & 15, fk = (lane >> 4) * 8;
    const ushort_t* pa  = &As [(wm + fr)*32 + fk];
    const ushort_t* pb1 = &Bs1[(wn + fr)*32 + fk];
    const ushort_t* pb2 = (MODE == 3) ? &Bs2[(wn + fr)*32 + fk] : nullptr;

    floatx4 acc1[4][4];
    floatx4 acc2[(MODE == 3) ? 4 : 1][(MODE == 3) ? 4 : 1];
    #pragma unroll
    for (int i = 0; i < 4; i++)
        #pragma unroll
        for (int j = 0; j < 4; j++) {
            acc1[i][j] = (floatx4)(0.f);
            if (MODE == 3) acc2[i][j] = (floatx4)(0.f);
        }

    for (int k0 = 0; k0 < K; k0 += 32) {
        gload16(gA  + k0,            lA);
        gload16(gA  + (size_t)64*K + k0, lA  + 64*32);
        gload16(gB1 + k0,            lB1);
        gload16(gB1 + (size_t)64*K + k0, lB1 + 64*32);
        if (MODE == 3) {
            gload16(gB2 + k0,            lB2);
            gload16(gB2 + (size_t)64*K + k0, lB2 + 64*32);
        }
        __syncthreads();

        short8 a[4];
        #pragma unroll
        for (int mt = 0; mt < 4; mt++) a[mt] = *(const short8*)(pa + mt*16*32);
        {
            short8 b[4];
            #pragma unroll
            for (int nt = 0; nt < 4; nt++) b[nt] = *(const short8*)(pb1 + nt*16*32);
            #pragma unroll
            for (int mt = 0; mt < 4; mt++)
                #pragma unroll
                for (int nt = 0; nt < 4; nt++)
                    acc1[mt][nt] = __builtin_amdgcn_mfma_f32_16x16x32_bf16(
                        a[mt], b[nt], acc1[mt][nt], 0, 0, 0);
        }
        if (MODE == 3) {
            short8 b[4];
            #pragma unroll
            for (int nt = 0; nt < 4; nt++) b[nt] = *(const short8*)(pb2 + nt*16*32);
            #pragma unroll
            for (int mt = 0; mt < 4; mt++)
                #pragma unroll
                for (int nt = 0; nt < 4; nt++)
                    acc2[mt][nt] = __builtin_amdgcn_mfma_f32_16x16x32_bf16(
                        a[mt], b[nt], acc2[mt][nt], 0, 0, 0);
        }
        __syncthreads();
    }

    int ecol0 = n0 + wn + (lane & 15);
    int erow0 = m0 + wm + (lane >> 4) * 4;
    #pragma unroll
    for (int mt = 0; mt < 4; mt++) {
        #pragma unroll
        for (int nt = 0; nt < 4; nt++) {
            int col = ecol0 + nt * 16;
            #pragma unroll
            for (int r = 0; r < 4; r++) {
                int row = erow0 + mt * 16 + r;
                size_t idx = (size_t)row * N + col;
                if (MODE == 3) {
                    float x1 = acc1[mt][nt][r] + bias1[col];
                    float x2 = acc2[mt][nt][r] + bias2[col];
                    float h = x1 / (1.f + __expf(-x1)) * x2;
                    ((ushort_t*)Cv)[idx] = f2bf(h);
                } else {
                    ((float*)Cv)[idx] = acc1[mt][nt][r] + bias1[col] + R[idx];
                }
            }
        }
    }
}

// ------- sparse MoE up-proj: rows gathered via idx list, dual-B SwiGLU -----
// A = x2 bf16 [NTOK,K]; C compact [row,N] bf16. Grid y covers NTOK/128 tiles.
__global__ __launch_bounds__(256)
void mgemm_up(const ushort_t* __restrict__ A, const int* __restrict__ idxl,
              const int* __restrict__ counts, int e,
              const ushort_t* __restrict__ B1, const float* __restrict__ bias1,
              const ushort_t* __restrict__ B2, const float* __restrict__ bias2,
              ushort_t* __restrict__ C, int N, int K)
{
    int cnt = counts[e];
    int m0 = blockIdx.y * 128;
    if (m0 >= cnt) return;

    __shared__ __align__(16) ushort_t As [128*32];
    __shared__ __align__(16) ushort_t Bs1[128*32];
    __shared__ __align__(16) ushort_t Bs2[128*32];

    int tid = threadIdx.x;
    int n0 = blockIdx.x * 128;
    int trow = tid >> 2;
    int tcol = (tid & 3) * 8;
    int r0 = m0 + trow, r1 = m0 + 64 + trow;
    int t0 = (r0 < cnt) ? idxl[r0] : 0;
    int t1 = (r1 < cnt) ? idxl[r1] : 0;
    const ushort_t* gA0 = A + (size_t)t0 * K + tcol;
    const ushort_t* gA1 = A + (size_t)t1 * K + tcol;
    const ushort_t* gB1 = B1 + (size_t)(n0 + trow) * K + tcol;
    const ushort_t* gB2 = B2 + (size_t)(n0 + trow) * K + tcol;
    ushort_t* lA  = &As [trow*32 + tcol];
    ushort_t* lB1 = &Bs1[trow*32 + tcol];
    ushort_t* lB2 = &Bs2[trow*32 + tcol];

    int wave = tid >> 6, lane = tid & 63;
    int wm = (wave >> 1) * 64, wn = (wave & 1) * 64;
    int fr = lane & 15, fk = (lane >> 4) * 8;
    const ushort_t* pa  = &As [(wm + fr)*32 + fk];
    const ushort_t* pb1 = &Bs1[(wn + fr)*32 + fk];
    const ushort_t* pb2 = &Bs2[(wn + fr)*32 + fk];

    floatx4 acc1[4][4], acc2[4][4];
    #pragma unroll
    for (int i = 0; i < 4; i++)
        #pragma unroll
        for (int j = 0; j < 4; j++) { acc1[i][j] = (floatx4)(0.f); acc2[i][j] = (floatx4)(0.f); }

    for (int k0 = 0; k0 < K; k0 += 32) {
        gload16(gA0 + k0, lA);
        gload16(gA1 + k0, lA + 64*32);
        gload16(gB1 + k0, lB1);
        gload16(gB1 + (size_t)64*K + k0, lB1 + 64*32);
        gload16(gB2 + k0, lB2);
        gload16(gB2 + (size_t)64*K + k0, lB2 + 64*32);
        __syncthreads();

        short8 a[4];
        #pragma unroll
        for (int mt = 0; mt < 4; mt++) a[mt] = *(const short8*)(pa + mt*16*32);
        {
            short8 b[4];
            #pragma unroll
            for (int nt = 0; nt < 4; nt++) b[nt] = *(const short8*)(pb1 + nt*16*32);
            #pragma unroll
            for (int mt = 0; mt < 4; mt++)
                #pragma unroll
                for (int nt = 0; nt < 4; nt++)
                    acc1[mt][nt] = __builtin_amdgcn_mfma_f32_16x16x32_bf16(
                        a[mt], b[nt], acc1[mt][nt], 0, 0, 0);
        }
        {
            short8 b[4];
            #pragma unroll
            for (int nt = 0; nt < 4; nt++) b[nt] = *(const short8*)(pb2 + nt*16*32);
            #pragma unroll
            for (int mt = 0; mt < 4; mt++)
                #pragma unroll
                for (int nt = 0; nt < 4; nt++)
                    acc2[mt][nt] = __builtin_amdgcn_mfma_f32_16x16x32_bf16(
                        a[mt], b[nt], acc2[mt][nt], 0, 0, 0);
        }
        __syncthreads();
    }

    int ecol0 = n0 + wn + (lane & 15);
    int erow0 = m0 + wm + (lane >> 4) * 4;
    #pragma unroll
    for (int mt = 0; mt < 4; mt++) {
        #pragma unroll
        for (int nt = 0; nt < 4; nt++) {
            int col = ecol0 + nt * 16;
            #pragma unroll
            for (int r = 0; r < 4; r++) {
                int row = erow0 + mt * 16 + r;
                float x1 = acc1[mt][nt][r] + bias1[col];
                float x2 = acc2[mt][nt][r] + bias2[col];
                float h = x1 / (1.f + __expf(-x1)) * x2;
                C[(size_t)row * N + col] = f2bf(h);
            }
        }
    }
}

// ------- sparse MoE down-proj: A compact [row,K]; scatter out[token] += w*row
__global__ __launch_bounds__(256)
void mgemm_down(const ushort_t* __restrict__ A, const int* __restrict__ idxl,
                const float* __restrict__ wgtl, const int* __restrict__ counts, int e,
                const ushort_t* __restrict__ B1, const float* __restrict__ bias1,
                float* __restrict__ out, int N, int K)
{
    int cnt = counts[e];
    int m0 = blockIdx.y * 128;
    if (m0 >= cnt) return;

    __shared__ __align__(16) ushort_t As [128*32];
    __shared__ __align__(16) ushort_t Bs1[128*32];

    int tid = threadIdx.x;
    int n0 = blockIdx.x * 128;
    int trow = tid >> 2;
    int tcol = (tid & 3) * 8;
    const ushort_t* gA  = A  + (size_t)(m0 + trow) * K + tcol;
    const ushort_t* gB1 = B1 + (size_t)(n0 + trow) * K + tcol;
    ushort_t* lA  = &As [trow*32 + tcol];
    ushort_t* lB1 = &Bs1[trow*32 + tcol];

    int wave = tid >> 6, lane = tid & 63;
    int wm = (wave >> 1) * 64, wn = (wave & 1) * 64;
    int fr = lane & 15, fk = (lane >> 4) * 8;
    const ushort_t* pa  = &As [(wm + fr)*32 + fk];
    const ushort_t* pb1 = &Bs1[(wn + fr)*32 + fk];

    floatx4 acc1[4][4];
    #pragma unroll
    for (int i = 0; i < 4; i++)
        #pragma unroll
        for (int j = 0; j < 4; j++) acc1[i][j] = (floatx4)(0.f);

    for (int k0 = 0; k0 < K; k0 += 32) {
        gload16(gA + k0,             lA);
        gload16(gA + (size_t)64*K + k0, lA + 64*32);
        gload16(gB1 + k0,            lB1);
        gload16(gB1 + (size_t)64*K + k0, lB1 + 64*32);
        __syncthreads();

        short8 a[4];
        #pragma unroll
        for (int mt = 0; mt < 4; mt++) a[mt] = *(const short8*)(pa + mt*16*32);
        short8 b[4];
        #pragma unroll
        for (int nt = 0; nt < 4; nt++) b[nt] = *(const short8*)(pb1 + nt*16*32);
        #pragma unroll
        for (int mt = 0; mt < 4; mt++)
            #pragma unroll
            for (int nt = 0; nt < 4; nt++)
                acc1[mt][nt] = __builtin_amdgcn_mfma_f32_16x16x32_bf16(
                    a[mt], b[nt], acc1[mt][nt], 0, 0, 0);
        __syncthreads();
    }

    int ecol0 = n0 + wn + (lane & 15);
    int erow0 = m0 + wm + (lane >> 4) * 4;
    #pragma unroll
    for (int mt = 0; mt < 4; mt++) {
        int rowb = erow0 + mt * 16;
        int tok[4]; float wv[4];
        #pragma unroll
        for (int r = 0; r < 4; r++) {
            int row = rowb + r;
            tok[r] = (row < cnt) ? idxl[row] : -1;
            wv[r]  = (row < cnt) ? wgtl[row] : 0.f;
        }
        #pragma unroll
        for (int nt = 0; nt < 4; nt++) {
            int col = ecol0 + nt * 16;
            #pragma unroll
            for (int r = 0; r < 4; r++) {
                if (tok[r] >= 0)
                    out[(size_t)tok[r] * N + col] += wv[r] * (acc1[mt][nt][r] + bias1[col]);
            }
        }
    }
}

// ---------------- MFMA flash attention (bf16 in/out, f32 accum) -----------
// Grid: B*H*(S/64) blocks, 256 threads = 4 waves. Wave w owns q rows
// s0+w*16 .. s0+w*16+15, Q held in registers (2 A-frags of 16x16x32).
// Per 64-wide K/V tile: K staged [64][72] row-major (72-pad => 144B rows,
// bank quad rotates by 4/row -> balanced b128 reads, no swizzle needed);
// V staged transposed [d][k] in [64][72] (transpose on global-read side:
// lane reads column d=lane via coalesced 128B wave transactions).
// Softmax online in registers; P -> per-wave LDS region (bf16) to reshape
// into A-fragment layout for the PV MFMA.
__global__ __launch_bounds__(256)
void fattn_kernel(const ushort_t* __restrict__ q, const ushort_t* __restrict__ k,
                  const ushort_t* __restrict__ v, ushort_t* __restrict__ ctx)
{
    __shared__ __align__(16) ushort_t Ks[64*72];     // [k][d] padded
    __shared__ __align__(16) ushort_t Vt[64*72];     // [d][k] padded
    __shared__ __align__(16) ushort_t Ps[4][16*72];  // per-wave P [q][k]

    const int bid = blockIdx.x;
    const int qt = bid & (S_/64 - 1);
    const int h  = (bid >> 4) & (H_ - 1);
    const int b  = bid >> 8;
    const int tid = threadIdx.x;
    const int wave = tid >> 6, lane = tid & 63;
    const int RS = H_ * DK_;                         // token stride (elems)
    const size_t headbase = ((size_t)b * S_ * H_ + h) * DK_;
    const int s0 = qt * 64;
    const int lr = lane & 15, lg = lane >> 4;

    // Q fragments in registers: A row = lane&15, k = (lane>>4)*8 + half*32
    short8 qf0, qf1;
    {
        const ushort_t* qp = q + headbase + (size_t)(s0 + wave*16 + lr) * RS + lg * 8;
        qf0 = *(const short8*)qp;
        qf1 = *(const short8*)(qp + 32);
    }

    floatx4 O[4];
    float m_i[4], l_i[4];
    #pragma unroll
    for (int i = 0; i < 4; i++) { O[i] = (floatx4)(0.f); m_i[i] = -1e30f; l_i[i] = 0.f; }

    const int kr = tid >> 3, kc = (tid & 7) * 8;     // K staging assignment
    ushort_t* pw = Ps[wave];

    for (int t = 0; t < S_/64; t++) {
        const int kbase = t * 64;
        __syncthreads();                              // prev-iter reads done
        // ---- stage K tile [64][72], coalesced b128 global reads ----
        {
            const ushort_t* kp = k + headbase + (size_t)(kbase + kr) * RS + kc;
            short8 k0 = *(const short8*)kp;
            short8 k1 = *(const short8*)(kp + (size_t)32 * RS);
            *(short8*)&Ks[kr*72 + kc]        = k0;
            *(short8*)&Ks[(kr + 32)*72 + kc] = k1;
        }
        // ---- stage V^T: lane reads column d=lane (128B coalesced per j) ----
        {
            const ushort_t* vp = v + headbase + (size_t)(kbase + wave*16) * RS + lane;
            short8 w0, w1;
            #pragma unroll
            for (int j = 0; j < 8; j++) {
                ((ushort_t*)&w0)[j] = vp[(size_t)j * RS];
                ((ushort_t*)&w1)[j] = vp[(size_t)(j + 8) * RS];
            }
            *(short8*)&Vt[lane*72 + wave*16]     = w0;
            *(short8*)&Vt[lane*72 + wave*16 + 8] = w1;
        }
        __syncthreads();

        // ---- S = (Q K^T) * 0.125 ; S[q=(lg*4+r)][kcol=lr+16*nt] ----
        floatx4 sacc[4];
        #pragma unroll
        for (int nt = 0; nt < 4; nt++) sacc[nt] = (floatx4)(0.f);
        #pragma unroll
        for (int nt = 0; nt < 4; nt++) {
            short8 b0 = *(const short8*)&Ks[(lr + nt*16)*72 + lg*8];
            sacc[nt] = __builtin_amdgcn_mfma_f32_16x16x32_bf16(qf0, b0, sacc[nt], 0, 0, 0);
            short8 b1 = *(const short8*)&Ks[(lr + nt*16)*72 + 32 + lg*8];
            sacc[nt] = __builtin_amdgcn_mfma_f32_16x16x32_bf16(qf1, b1, sacc[nt], 0, 0, 0);
        }

        // ---- online softmax: row reduce across the 16-lane column group ----
        float alpha[4];
        #pragma unroll
        for (int r = 0; r < 4; r++) {
            float rm = -1e30f;
            #pragma unroll
            for (int nt = 0; nt < 4; nt++) { sacc[nt][r] *= 0.125f; rm = fmaxf(rm, sacc[nt][r]); }
            #pragma unroll
            for (int o = 1; o < 16; o <<= 1) rm = fmaxf(rm, __shfl_xor(rm, o, 64));
            float nm = fmaxf(m_i[r], rm);
            alpha[r] = __expf(m_i[r] - nm);
            m_i[r] = nm;
            float rs = 0.f;
            #pragma unroll
            for (int nt = 0; nt < 4; nt++) { sacc[nt][r] = __expf(sacc[nt][r] - nm); rs += sacc[nt][r]; }
            #pragma unroll
            for (int o = 1; o < 16; o <<= 1) rs += __shfl_xor(rs, o, 64);
            l_i[r] = l_i[r] * alpha[r] + rs;
        }

        // ---- P -> per-wave LDS (bf16), reshaping for A-fragment reads ----
        #pragma unroll
        for (int nt = 0; nt < 4; nt++)
            #pragma unroll
            for (int r = 0; r < 4; r++)
                pw[(lg*4 + r)*72 + lr + nt*16] = f2bf(sacc[nt][r]);

        // ---- O rescale, then O += P V ----
        #pragma unroll
        for (int nt = 0; nt < 4; nt++)
            #pragma unroll
            for (int r = 0; r < 4; r++)
                O[nt][r] *= alpha[r];

        asm volatile("s_waitcnt lgkmcnt(0)" ::: "memory");  // P writes visible (same wave)

        #pragma unroll
        for (int kh = 0; kh < 2; kh++) {
            short8 pa = *(const short8*)&pw[lr*72 + kh*32 + lg*8];
            #pragma unroll
            for (int nt = 0; nt < 4; nt++) {
                short8 bv = *(const short8*)&Vt[(lr + nt*16)*72 + kh*32 + lg*8];
                O[nt] = __builtin_amdgcn_mfma_f32_16x16x32_bf16(pa, bv, O[nt], 0, 0, 0);
            }
        }
    }

    // ---- epilogue: O/l via per-wave LDS transpose for coalesced stores ----
    #pragma unroll
    for (int r = 0; r < 4; r++) {
        float inv = 1.f / l_i[r];
        #pragma unroll
        for (int nt = 0; nt < 4; nt++)
            pw[(lg*4 + r)*72 + lr + nt*16] = f2bf(O[nt][r] * inv);
    }
    asm volatile("s_waitcnt lgkmcnt(0)" ::: "memory");
    {
        const int row = lane >> 2, c0 = (lane & 3) * 16;
        short8 o0 = *(const short8*)&pw[row*72 + c0];
        short8 o1 = *(const short8*)&pw[row*72 + c0 + 8];
        ushort_t* gp = ctx + headbase + (size_t)(s0 + wave*16 + row) * RS + c0;
        *(short8*)gp       = o0;
        *(short8*)(gp + 8) = o1;
    }
}

extern "C" void kernel_launch(void* const* d_in, const int* in_sizes, int n_in,
                              void* d_out, int out_size, void* d_ws, size_t ws_size,
                              hipStream_t stream)
{
    const float* x    = (const float*)d_in[0];
    const float* wq1  = (const float*)d_in[2];
    const float* bq1  = (const float*)d_in[3];
    const float* wq2  = (const float*)d_in[4];
    const float* bq2  = (const float*)d_in[5];
    const float* wk1  = (const float*)d_in[6];
    const float* bk1  = (const float*)d_in[7];
    const float* wk2  = (const float*)d_in[8];
    const float* bk2  = (const float*)d_in[9];
    const float* wv1  = (const float*)d_in[10];
    const float* bv1  = (const float*)d_in[11];
    const float* wv2  = (const float*)d_in[12];
    const float* bv2  = (const float*)d_in[13];
    const float* wo   = (const float*)d_in[14];
    const float* bo   = (const float*)d_in[15];
    const float* ln1g = (const float*)d_in[16];
    const float* ln1b = (const float*)d_in[17];
    const float* ln2g = (const float*)d_in[18];
    const float* ln2b = (const float*)d_in[19];
    const float* gw   = (const float*)d_in[20];
    const float* gb   = (const float*)d_in[21];
    const float* ew1  = (const float*)d_in[22];
    const float* eb1  = (const float*)d_in[23];
    const float* ew2  = (const float*)d_in[24];
    const float* eb2  = (const float*)d_in[25];
    const float* ew3  = (const float*)d_in[26];
    const float* eb3  = (const float*)d_in[27];
    float* out = (float*)d_out;

    char* w = (char*)d_ws;
    ushort_t* wq1t = (ushort_t*)w; w += (size_t)D_*D_*2;
    ushort_t* wq2t = (ushort_t*)w; w += (size_t)D_*D_*2;
    ushort_t* wk1t = (ushort_t*)w; w += (size_t)D_*D_*2;
    ushort_t* wk2t = (ushort_t*)w; w += (size_t)D_*D_*2;
    ushort_t* wv1t = (ushort_t*)w; w += (size_t)D_*D_*2;
    ushort_t* wv2t = (ushort_t*)w; w += (size_t)D_*D_*2;
    ushort_t* wot  = (ushort_t*)w; w += (size_t)D_*D_*2;
    ushort_t* e1t  = (ushort_t*)w; w += (size_t)D_*F_*2;
    ushort_t* e3t  = (ushort_t*)w; w += (size_t)D_*F_*2;
    ushort_t* e2t  = (ushort_t*)w; w += (size_t)D_*F_*2;
    ushort_t* x2h  = (ushort_t*)w; w += (size_t)NTOK*D_*2;
    ushort_t* qh   = (ushort_t*)w; w += (size_t)NTOK*D_*2;
    ushort_t* kh   = (ushort_t*)w; w += (size_t)NTOK*D_*2;
    ushort_t* vh   = (ushort_t*)w; w += (size_t)NTOK*D_*2;
    ushort_t* ctxh = (ushort_t*)w; w += (size_t)NTOK*D_*2;
    ushort_t* x2bh = (ushort_t*)w; w += (size_t)NTOK*D_*2;
    ushort_t* hAh  = (ushort_t*)w; w += (size_t)NTOK*F_*2;
    int*      cnts = (int*)w;      w += 256;
    int*      idxl = (int*)w;      w += (size_t)E_*NTOK*4;
    float*    wgtl = (float*)w;    w += (size_t)E_*NTOK*4;

    dim3 blk(256);

    W7 p7;
    p7.s[0]=wq1; p7.d[0]=wq1t; p7.s[1]=wq2; p7.d[1]=wq2t;
    p7.s[2]=wk1; p7.d[2]=wk1t; p7.s[3]=wk2; p7.d[3]=wk2t;
    p7.s[4]=wv1; p7.d[4]=wv1t; p7.s[5]=wv2; p7.d[5]=wv2t;
    p7.s[6]=wo;  p7.d[6]=wot;
    transpose7<<<dim3(32,32,7), blk, 0, stream>>>(p7, D_, D_);

    // --- pre-norm attention ---
    ln_kernel<<<NTOK, blk, 0, stream>>>(x, ln1g, ln1b, x2h);
    dim3 gDD(D_/128, NTOK/128);
    mgemm<3><<<gDD, blk, 0, stream>>>(x2h, wq1t, bq1, wq2t, bq2, nullptr, qh, NTOK, D_, D_);
    mgemm<3><<<gDD, blk, 0, stream>>>(x2h, wk1t, bk1, wk2t, bk2, nullptr, kh, NTOK, D_, D_);
    mgemm<3><<<gDD, blk, 0, stream>>>(x2h, wv1t, bv1, wv2t, bv2, nullptr, vh, NTOK, D_, D_);
    fattn_kernel<<<B_ * H_ * (S_/64), blk, 0, stream>>>(qh, kh, vh, ctxh);
    mgemm<1><<<gDD, blk, 0, stream>>>(ctxh, wot, bo, nullptr, nullptr, x, out, NTOK, D_, D_);

    // --- pre-norm MoE SwiGLU FFN (top-2 sparse), gate fused into LN ---
    hipMemsetAsync(cnts, 0, 256, stream);
    ln_gate_kernel<<<NTOK, blk, 0, stream>>>(out, ln2g, ln2b, x2bh, gw, gb,
                                             cnts, idxl, wgtl);

    dim3 gFD(F_/128, NTOK/128);
    for (int e = 0; e < E_; e++) {
        transpose_cvt<<<dim3(F_/32, D_/32, 2), blk, 0, stream>>>(
            ew1 + (size_t)e*D_*F_, e1t, ew3 + (size_t)e*D_*F_, e3t, D_, F_);
        transpose_cvt<<<dim3(D_/32, F_/32, 1), blk, 0, stream>>>(
            ew2 + (size_t)e*F_*D_, e2t, nullptr, nullptr, F_, D_);
        mgemm_up<<<gFD, blk, 0, stream>>>(x2bh, idxl + (size_t)e*NTOK, cnts, e,
                                          e1t, eb1 + (size_t)e*F_, e3t, eb3 + (size_t)e*F_,
                                          hAh, F_, D_);
        mgemm_down<<<gDD, blk, 0, stream>>>(hAh, idxl + (size_t)e*NTOK, wgtl + (size_t)e*NTOK,
                                            cnts, e, e2t, eb2 + (size_t)e*D_, out, D_, F_);
    }
}

// Round 3
// 1388.030 us; speedup vs baseline: 1.2847x; 1.0526x over previous
//
#include <hip/hip_runtime.h>
#include <math.h>

#define B_ 4
#define S_ 1024
#define D_ 1024
#define F_ 2048
#define H_ 16
#define E_ 8
#define DK_ 64
#define NTOK (B_*S_)

typedef unsigned short ushort_t;
typedef __attribute__((ext_vector_type(8))) short short8;
typedef __attribute__((ext_vector_type(4))) float floatx4;

// ---- bf16 helpers (RNE) ----
__device__ __forceinline__ ushort_t f2bf(float f) {
    unsigned u = __float_as_uint(f);
    unsigned r = (u + 0x7fffu + ((u >> 16) & 1u)) >> 16;
    return (ushort_t)r;
}
__device__ __forceinline__ float bf2f(ushort_t h) {
    return __uint_as_float(((unsigned)h) << 16);
}

// ---- async global->LDS 16B ----
__device__ __forceinline__ void gload16(const void* g, void* l) {
    __builtin_amdgcn_global_load_lds(
        (const __attribute__((address_space(1))) unsigned*)g,
        (__attribute__((address_space(3))) unsigned*)l, 16, 0, 0);
}

// ---------------- block reductions (256 threads = 4 waves) ----------------
__device__ __forceinline__ float blockReduceSum256(float v, volatile float* sred) {
    int tid = threadIdx.x;
    #pragma unroll
    for (int o = 32; o > 0; o >>= 1) v += __shfl_down(v, o, 64);
    __syncthreads();
    if ((tid & 63) == 0) sred[tid >> 6] = v;
    __syncthreads();
    return sred[0] + sred[1] + sred[2] + sred[3];
}

// ---------------- LayerNorm: one block per row; writes bf16 ---------------
__global__ __launch_bounds__(256)
void ln_kernel(const float* __restrict__ x, const float* __restrict__ g,
               const float* __restrict__ b, ushort_t* __restrict__ yh) {
    __shared__ float sred[4];
    int row = blockIdx.x;
    int tid = threadIdx.x;
    const float* xr = x + (size_t)row * D_;
    float v[4];
    float s = 0.f;
    #pragma unroll
    for (int i = 0; i < 4; i++) { v[i] = xr[tid + 256*i]; s += v[i]; }
    float mean = blockReduceSum256(s, sred) * (1.f / D_);
    float s2 = 0.f;
    #pragma unroll
    for (int i = 0; i < 4; i++) { float d = v[i] - mean; s2 += d * d; }
    float var = blockReduceSum256(s2, sred) * (1.f / D_);
    float rstd = rsqrtf(var + 1e-5f);
    #pragma unroll
    for (int i = 0; i < 4; i++) {
        int c = tid + 256*i;
        float r = (v[i] - mean) * rstd * g[c] + b[c];
        yh[(size_t)row * D_ + c] = f2bf(r);
    }
}

// ------- LayerNorm fused with MoE gate (softmax + top-2, NO atomics) ------
// One block per token row. LN as before; each thread accumulates its 4
// columns' contribution to the 8 expert logits; packed shuffle reduce;
// thread 0 does softmax/top-2 and writes packed top-2 ids + weights.
__global__ __launch_bounds__(256)
void ln_gate_kernel(const float* __restrict__ x, const float* __restrict__ g,
                    const float* __restrict__ b, ushort_t* __restrict__ yh,
                    const float* __restrict__ gw, const float* __restrict__ gb,
                    int* __restrict__ tope, float2* __restrict__ topw) {
    __shared__ float sred[4];
    __shared__ float sgate[4][E_];
    int row = blockIdx.x;
    int tid = threadIdx.x;
    const float* xr = x + (size_t)row * D_;
    float v[4];
    float s = 0.f;
    #pragma unroll
    for (int i = 0; i < 4; i++) { v[i] = xr[tid + 256*i]; s += v[i]; }
    float mean = blockReduceSum256(s, sred) * (1.f / D_);
    float s2 = 0.f;
    #pragma unroll
    for (int i = 0; i < 4; i++) { float d = v[i] - mean; s2 += d * d; }
    float var = blockReduceSum256(s2, sred) * (1.f / D_);
    float rstd = rsqrtf(var + 1e-5f);

    float p[E_];
    #pragma unroll
    for (int e = 0; e < E_; e++) p[e] = 0.f;
    #pragma unroll
    for (int i = 0; i < 4; i++) {
        int c = tid + 256*i;
        float r = (v[i] - mean) * rstd * g[c] + b[c];
        yh[(size_t)row * D_ + c] = f2bf(r);
        const float* gwr = gw + (size_t)c * E_;
        #pragma unroll
        for (int e = 0; e < E_; e++) p[e] += r * gwr[e];
    }
    // packed 8-logit wave reduce
    #pragma unroll
    for (int o = 32; o > 0; o >>= 1)
        #pragma unroll
        for (int e = 0; e < E_; e++) p[e] += __shfl_down(p[e], o, 64);
    __syncthreads();
    if ((tid & 63) == 0) {
        #pragma unroll
        for (int e = 0; e < E_; e++) sgate[tid >> 6][e] = p[e];
    }
    __syncthreads();
    if (tid == 0) {
        float q[E_];
        float mx = -1e30f;
        #pragma unroll
        for (int e = 0; e < E_; e++) {
            q[e] = sgate[0][e] + sgate[1][e] + sgate[2][e] + sgate[3][e] + gb[e];
            mx = fmaxf(mx, q[e]);
        }
        float sum = 0.f;
        #pragma unroll
        for (int e = 0; e < E_; e++) { q[e] = expf(q[e] - mx); sum += q[e]; }
        #pragma unroll
        for (int e = 0; e < E_; e++) q[e] /= sum;
        int i1 = 0;
        #pragma unroll
        for (int e = 1; e < E_; e++) if (q[e] > q[i1]) i1 = e;
        int i2 = (i1 == 0) ? 1 : 0;
        #pragma unroll
        for (int e = 0; e < E_; e++) if (e != i2 && e != i1 && q[e] > q[i2]) i2 = e;
        float denom = q[i1] + q[i2] + 1e-6f;
        tope[row] = i1 | (i2 << 8);
        topw[row] = make_float2(q[i1] / denom, q[i2] / denom);
    }
}

// ------- build per-expert token lists (deterministic compaction) ----------
// 8 blocks (one per expert) x 256 threads. Ballot-prefix within wave,
// LDS scan across the 4 waves, running block offset. No global atomics.
__global__ __launch_bounds__(256)
void build_lists(const int* __restrict__ tope, const float2* __restrict__ topw,
                 int* __restrict__ counts, int* __restrict__ idxl,
                 float* __restrict__ wgtl)
{
    const int e = blockIdx.x;
    const int tid = threadIdx.x;
    const int lane = tid & 63, wv = tid >> 6;
    __shared__ int wsum[4];
    __shared__ int sbase;
    if (tid == 0) sbase = 0;
    __syncthreads();
    int* il = idxl + (size_t)e * NTOK;
    float* wl = wgtl + (size_t)e * NTOK;
    for (int t0 = 0; t0 < NTOK; t0 += 256) {
        int t = t0 + tid;
        int pk = tope[t];
        int i1 = pk & 255, i2 = (pk >> 8) & 255;
        bool m = (i1 == e) || (i2 == e);
        float2 wp = topw[t];
        float w = (i1 == e) ? wp.x : wp.y;
        unsigned long long mask = __ballot(m);
        int wpos = __popcll(mask & ((1ull << lane) - 1ull));
        int wcnt = __popcll(mask);
        if (lane == 0) wsum[wv] = wcnt;
        __syncthreads();                 // wsum ready; sbase stable
        int base = sbase;
        int pre = 0;
        #pragma unroll
        for (int i = 0; i < 4; i++) if (i < wv) pre += wsum[i];
        if (m) {
            il[base + pre + wpos] = t;
            wl[base + pre + wpos] = w;
        }
        __syncthreads();                 // all read sbase before update
        if (tid == 0) sbase = base + wsum[0] + wsum[1] + wsum[2] + wsum[3];
    }
    __syncthreads();
    if (tid == 0) counts[e] = sbase;
}

// ---------------- transpose+convert: src[R,C] f32 -> dst[C,R] bf16 --------
__global__ __launch_bounds__(256)
void transpose_cvt(const float* __restrict__ s1, ushort_t* __restrict__ d1,
                   const float* __restrict__ s2, ushort_t* __restrict__ d2,
                   int R, int C)
{
    const float* s = blockIdx.z ? s2 : s1;
    ushort_t* d = blockIdx.z ? d2 : d1;
    __shared__ float t[32][33];
    int r0 = blockIdx.y * 32, c0 = blockIdx.x * 32;
    int lr = threadIdx.x >> 3, lc = (threadIdx.x & 7) * 4;
    float4 v = *(const float4*)(s + (size_t)(r0 + lr) * C + c0 + lc);
    t[lr][lc+0] = v.x; t[lr][lc+1] = v.y; t[lr][lc+2] = v.z; t[lr][lc+3] = v.w;
    __syncthreads();
    ushort4 o;
    o.x = f2bf(t[lc+0][lr]); o.y = f2bf(t[lc+1][lr]);
    o.z = f2bf(t[lc+2][lr]); o.w = f2bf(t[lc+3][lr]);
    *(ushort4*)(d + (size_t)(c0 + lr) * R + r0 + lc) = o;
}

struct W7 { const float* s[7]; ushort_t* d[7]; };
__global__ __launch_bounds__(256)
void transpose7(W7 p, int R, int C)
{
    const float* s = p.s[blockIdx.z];
    ushort_t* d = p.d[blockIdx.z];
    __shared__ float t[32][33];
    int r0 = blockIdx.y * 32, c0 = blockIdx.x * 32;
    int lr = threadIdx.x >> 3, lc = (threadIdx.x & 7) * 4;
    float4 v = *(const float4*)(s + (size_t)(r0 + lr) * C + c0 + lc);
    t[lr][lc+0] = v.x; t[lr][lc+1] = v.y; t[lr][lc+2] = v.z; t[lr][lc+3] = v.w;
    __syncthreads();
    ushort4 o;
    o.x = f2bf(t[lc+0][lr]); o.y = f2bf(t[lc+1][lr]);
    o.z = f2bf(t[lc+2][lr]); o.w = f2bf(t[lc+3][lr]);
    *(ushort4*)(d + (size_t)(c0 + lr) * R + r0 + lc) = o;
}

// ---------------- MFMA bf16 GEMM: C = A[M,K] @ B^T (B stored [N,K]) ------
// 128x128 tile, BK=32, 256 thr (2x2 waves of 64x64), 16x16x32 MFMA.
// MODE 1: Cf = acc + bias1 + R                (f32 out)
// MODE 3: Ch = silu(acc1+bias1)*(acc2+bias2)  (bf16 out, dual B)
template<int MODE>
__global__ __launch_bounds__(256)
void mgemm(const ushort_t* __restrict__ A, const ushort_t* __restrict__ B1,
           const float* __restrict__ bias1, const ushort_t* __restrict__ B2,
           const float* __restrict__ bias2, const float* __restrict__ R,
           void* __restrict__ Cv, int M, int N, int K)
{
    __shared__ __align__(16) ushort_t As [128*32];
    __shared__ __align__(16) ushort_t Bs1[128*32];
    __shared__ __align__(16) ushort_t Bs2[(MODE == 3) ? 128*32 : 16];

    int tid = threadIdx.x;
    int m0 = blockIdx.y * 128, n0 = blockIdx.x * 128;
    int trow = tid >> 2;             // 0..63
    int tcol = (tid & 3) * 8;        // k-element offset (16B chunks)
    const ushort_t* gA  = A  + (size_t)(m0 + trow) * K + tcol;
    const ushort_t* gB1 = B1 + (size_t)(n0 + trow) * K + tcol;
    const ushort_t* gB2 = (MODE == 3) ? B2 + (size_t)(n0 + trow) * K + tcol : nullptr;
    ushort_t* lA  = &As [trow*32 + tcol];
    ushort_t* lB1 = &Bs1[trow*32 + tcol];
    ushort_t* lB2 = (MODE == 3) ? &Bs2[trow*32 + tcol] : nullptr;

    int wave = tid >> 6, lane = tid & 63;
    int wm = (wave >> 1) * 64, wn = (wave & 1) * 64;
    int fr = lane & 15, fk = (lane >> 4) * 8;
    const ushort_t* pa  = &As [(wm + fr)*32 + fk];
    const ushort_t* pb1 = &Bs1[(wn + fr)*32 + fk];
    const ushort_t* pb2 = (MODE == 3) ? &Bs2[(wn + fr)*32 + fk] : nullptr;

    floatx4 acc1[4][4];
    floatx4 acc2[(MODE == 3) ? 4 : 1][(MODE == 3) ? 4 : 1];
    #pragma unroll
    for (int i = 0; i < 4; i++)
        #pragma unroll
        for (int j = 0; j < 4; j++) {
            acc1[i][j] = (floatx4)(0.f);
            if (MODE == 3) acc2[i][j] = (floatx4)(0.f);
        }

    for (int k0 = 0; k0 < K; k0 += 32) {
        gload16(gA  + k0,            lA);
        gload16(gA  + (size_t)64*K + k0, lA  + 64*32);
        gload16(gB1 + k0,            lB1);
        gload16(gB1 + (size_t)64*K + k0, lB1 + 64*32);
        if (MODE == 3) {
            gload16(gB2 + k0,            lB2);
            gload16(gB2 + (size_t)64*K + k0, lB2 + 64*32);
        }
        __syncthreads();

        short8 a[4];
        #pragma unroll
        for (int mt = 0; mt < 4; mt++) a[mt] = *(const short8*)(pa + mt*16*32);
        {
            short8 b[4];
            #pragma unroll
            for (int nt = 0; nt < 4; nt++) b[nt] = *(const short8*)(pb1 + nt*16*32);
            #pragma unroll
            for (int mt = 0; mt < 4; mt++)
                #pragma unroll
                for (int nt = 0; nt < 4; nt++)
                    acc1[mt][nt] = __builtin_amdgcn_mfma_f32_16x16x32_bf16(
                        a[mt], b[nt], acc1[mt][nt], 0, 0, 0);
        }
        if (MODE == 3) {
            short8 b[4];
            #pragma unroll
            for (int nt = 0; nt < 4; nt++) b[nt] = *(const short8*)(pb2 + nt*16*32);
            #pragma unroll
            for (int mt = 0; mt < 4; mt++)
                #pragma unroll
                for (int nt = 0; nt < 4; nt++)
                    acc2[mt][nt] = __builtin_amdgcn_mfma_f32_16x16x32_bf16(
                        a[mt], b[nt], acc2[mt][nt], 0, 0, 0);
        }
        __syncthreads();
    }

    int ecol0 = n0 + wn + (lane & 15);
    int erow0 = m0 + wm + (lane >> 4) * 4;
    #pragma unroll
    for (int mt = 0; mt < 4; mt++) {
        #pragma unroll
        for (int nt = 0; nt < 4; nt++) {
            int col = ecol0 + nt * 16;
            #pragma unroll
            for (int r = 0; r < 4; r++) {
                int row = erow0 + mt * 16 + r;
                size_t idx = (size_t)row * N + col;
                if (MODE == 3) {
                    float x1 = acc1[mt][nt][r] + bias1[col];
                    float x2 = acc2[mt][nt][r] + bias2[col];
                    float h = x1 / (1.f + __expf(-x1)) * x2;
                    ((ushort_t*)Cv)[idx] = f2bf(h);
                } else {
                    ((float*)Cv)[idx] = acc1[mt][nt][r] + bias1[col] + R[idx];
                }
            }
        }
    }
}

// ------- sparse MoE up-proj: rows gathered via idx list, dual-B SwiGLU -----
// A = x2 bf16 [NTOK,K]; C compact [row,N] bf16. Grid y covers NTOK/128 tiles.
__global__ __launch_bounds__(256)
void mgemm_up(const ushort_t* __restrict__ A, const int* __restrict__ idxl,
              const int* __restrict__ counts, int e,
              const ushort_t* __restrict__ B1, const float* __restrict__ bias1,
              const ushort_t* __restrict__ B2, const float* __restrict__ bias2,
              ushort_t* __restrict__ C, int N, int K)
{
    int cnt = counts[e];
    int m0 = blockIdx.y * 128;
    if (m0 >= cnt) return;

    __shared__ __align__(16) ushort_t As [128*32];
    __shared__ __align__(16) ushort_t Bs1[128*32];
    __shared__ __align__(16) ushort_t Bs2[128*32];

    int tid = threadIdx.x;
    int n0 = blockIdx.x * 128;
    int trow = tid >> 2;
    int tcol = (tid & 3) * 8;
    int r0 = m0 + trow, r1 = m0 + 64 + trow;
    int t0 = (r0 < cnt) ? idxl[r0] : 0;
    int t1 = (r1 < cnt) ? idxl[r1] : 0;
    const ushort_t* gA0 = A + (size_t)t0 * K + tcol;
    const ushort_t* gA1 = A + (size_t)t1 * K + tcol;
    const ushort_t* gB1 = B1 + (size_t)(n0 + trow) * K + tcol;
    const ushort_t* gB2 = B2 + (size_t)(n0 + trow) * K + tcol;
    ushort_t* lA  = &As [trow*32 + tcol];
    ushort_t* lB1 = &Bs1[trow*32 + tcol];
    ushort_t* lB2 = &Bs2[trow*32 + tcol];

    int wave = tid >> 6, lane = tid & 63;
    int wm = (wave >> 1) * 64, wn = (wave & 1) * 64;
    int fr = lane & 15, fk = (lane >> 4) * 8;
    const ushort_t* pa  = &As [(wm + fr)*32 + fk];
    const ushort_t* pb1 = &Bs1[(wn + fr)*32 + fk];
    const ushort_t* pb2 = &Bs2[(wn + fr)*32 + fk];

    floatx4 acc1[4][4], acc2[4][4];
    #pragma unroll
    for (int i = 0; i < 4; i++)
        #pragma unroll
        for (int j = 0; j < 4; j++) { acc1[i][j] = (floatx4)(0.f); acc2[i][j] = (floatx4)(0.f); }

    for (int k0 = 0; k0 < K; k0 += 32) {
        gload16(gA0 + k0, lA);
        gload16(gA1 + k0, lA + 64*32);
        gload16(gB1 + k0, lB1);
        gload16(gB1 + (size_t)64*K + k0, lB1 + 64*32);
        gload16(gB2 + k0, lB2);
        gload16(gB2 + (size_t)64*K + k0, lB2 + 64*32);
        __syncthreads();

        short8 a[4];
        #pragma unroll
        for (int mt = 0; mt < 4; mt++) a[mt] = *(const short8*)(pa + mt*16*32);
        {
            short8 b[4];
            #pragma unroll
            for (int nt = 0; nt < 4; nt++) b[nt] = *(const short8*)(pb1 + nt*16*32);
            #pragma unroll
            for (int mt = 0; mt < 4; mt++)
                #pragma unroll
                for (int nt = 0; nt < 4; nt++)
                    acc1[mt][nt] = __builtin_amdgcn_mfma_f32_16x16x32_bf16(
                        a[mt], b[nt], acc1[mt][nt], 0, 0, 0);
        }
        {
            short8 b[4];
            #pragma unroll
            for (int nt = 0; nt < 4; nt++) b[nt] = *(const short8*)(pb2 + nt*16*32);
            #pragma unroll
            for (int mt = 0; mt < 4; mt++)
                #pragma unroll
                for (int nt = 0; nt < 4; nt++)
                    acc2[mt][nt] = __builtin_amdgcn_mfma_f32_16x16x32_bf16(
                        a[mt], b[nt], acc2[mt][nt], 0, 0, 0);
        }
        __syncthreads();
    }

    int ecol0 = n0 + wn + (lane & 15);
    int erow0 = m0 + wm + (lane >> 4) * 4;
    #pragma unroll
    for (int mt = 0; mt < 4; mt++) {
        #pragma unroll
        for (int nt = 0; nt < 4; nt++) {
            int col = ecol0 + nt * 16;
            #pragma unroll
            for (int r = 0; r < 4; r++) {
                int row = erow0 + mt * 16 + r;
                float x1 = acc1[mt][nt][r] + bias1[col];
                float x2 = acc2[mt][nt][r] + bias2[col];
                float h = x1 / (1.f + __expf(-x1)) * x2;
                C[(size_t)row * N + col] = f2bf(h);
            }
        }
    }
}

// ------- sparse MoE down-proj: A compact [row,K]; scatter out[token] += w*row
__global__ __launch_bounds__(256)
void mgemm_down(const ushort_t* __restrict__ A, const int* __restrict__ idxl,
                const float* __restrict__ wgtl, const int* __restrict__ counts, int e,
                const ushort_t* __restrict__ B1, const float* __restrict__ bias1,
                float* __restrict__ out, int N, int K)
{
    int cnt = counts[e];
    int m0 = blockIdx.y * 128;
    if (m0 >= cnt) return;

    __shared__ __align__(16) ushort_t As [128*32];
    __shared__ __align__(16) ushort_t Bs1[128*32];

    int tid = threadIdx.x;
    int n0 = blockIdx.x * 128;
    int trow = tid >> 2;
    int tcol = (tid & 3) * 8;
    const ushort_t* gA  = A  + (size_t)(m0 + trow) * K + tcol;
    const ushort_t* gB1 = B1 + (size_t)(n0 + trow) * K + tcol;
    ushort_t* lA  = &As [trow*32 + tcol];
    ushort_t* lB1 = &Bs1[trow*32 + tcol];

    int wave = tid >> 6, lane = tid & 63;
    int wm = (wave >> 1) * 64, wn = (wave & 1) * 64;
    int fr = lane & 15, fk = (lane >> 4) * 8;
    const ushort_t* pa  = &As [(wm + fr)*32 + fk];
    const ushort_t* pb1 = &Bs1[(wn + fr)*32 + fk];

    floatx4 acc1[4][4];
    #pragma unroll
    for (int i = 0; i < 4; i++)
        #pragma unroll
        for (int j = 0; j < 4; j++) acc1[i][j] = (floatx4)(0.f);

    for (int k0 = 0; k0 < K; k0 += 32) {
        gload16(gA + k0,             lA);
        gload16(gA + (size_t)64*K + k0, lA + 64*32);
        gload16(gB1 + k0,            lB1);
        gload16(gB1 + (size_t)64*K + k0, lB1 + 64*32);
        __syncthreads();

        short8 a[4];
        #pragma unroll
        for (int mt = 0; mt < 4; mt++) a[mt] = *(const short8*)(pa + mt*16*32);
        short8 b[4];
        #pragma unroll
        for (int nt = 0; nt < 4; nt++) b[nt] = *(const short8*)(pb1 + nt*16*32);
        #pragma unroll
        for (int mt = 0; mt < 4; mt++)
            #pragma unroll
            for (int nt = 0; nt < 4; nt++)
                acc1[mt][nt] = __builtin_amdgcn_mfma_f32_16x16x32_bf16(
                    a[mt], b[nt], acc1[mt][nt], 0, 0, 0);
        __syncthreads();
    }

    int ecol0 = n0 + wn + (lane & 15);
    int erow0 = m0 + wm + (lane >> 4) * 4;
    #pragma unroll
    for (int mt = 0; mt < 4; mt++) {
        int rowb = erow0 + mt * 16;
        int tok[4]; float wv[4];
        #pragma unroll
        for (int r = 0; r < 4; r++) {
            int row = rowb + r;
            tok[r] = (row < cnt) ? idxl[row] : -1;
            wv[r]  = (row < cnt) ? wgtl[row] : 0.f;
        }
        #pragma unroll
        for (int nt = 0; nt < 4; nt++) {
            int col = ecol0 + nt * 16;
            #pragma unroll
            for (int r = 0; r < 4; r++) {
                if (tok[r] >= 0)
                    out[(size_t)tok[r] * N + col] += wv[r] * (acc1[mt][nt][r] + bias1[col]);
            }
        }
    }
}

// ---------------- MFMA flash attention (bf16 in/out, f32 accum) -----------
// Grid: B*H*(S/64) blocks, 256 threads = 4 waves. Wave w owns q rows
// s0+w*16 .. s0+w*16+15, Q held in registers (2 A-frags of 16x16x32).
// Per 64-wide K/V tile: K staged [64][72] row-major (72-pad => 144B rows,
// bank quad rotates by 4/row -> balanced b128 reads, no swizzle needed);
// V staged transposed [d][k] in [64][72] (transpose on global-read side:
// lane reads column d=lane via coalesced 128B wave transactions).
// Softmax online in registers; P -> per-wave LDS region (bf16) to reshape
// into A-fragment layout for the PV MFMA.
__global__ __launch_bounds__(256)
void fattn_kernel(const ushort_t* __restrict__ q, const ushort_t* __restrict__ k,
                  const ushort_t* __restrict__ v, ushort_t* __restrict__ ctx)
{
    __shared__ __align__(16) ushort_t Ks[64*72];     // [k][d] padded
    __shared__ __align__(16) ushort_t Vt[64*72];     // [d][k] padded
    __shared__ __align__(16) ushort_t Ps[4][16*72];  // per-wave P [q][k]

    const int bid = blockIdx.x;
    const int qt = bid & (S_/64 - 1);
    const int h  = (bid >> 4) & (H_ - 1);
    const int b  = bid >> 8;
    const int tid = threadIdx.x;
    const int wave = tid >> 6, lane = tid & 63;
    const int RS = H_ * DK_;                         // token stride (elems)
    const size_t headbase = ((size_t)b * S_ * H_ + h) * DK_;
    const int s0 = qt * 64;
    const int lr = lane & 15, lg = lane >> 4;

    // Q fragments in registers: A row = lane&15, k = (lane>>4)*8 + half*32
    short8 qf0, qf1;
    {
        const ushort_t* qp = q + headbase + (size_t)(s0 + wave*16 + lr) * RS + lg * 8;
        qf0 = *(const short8*)qp;
        qf1 = *(const short8*)(qp + 32);
    }

    floatx4 O[4];
    float m_i[4], l_i[4];
    #pragma unroll
    for (int i = 0; i < 4; i++) { O[i] = (floatx4)(0.f); m_i[i] = -1e30f; l_i[i] = 0.f; }

    const int kr = tid >> 3, kc = (tid & 7) * 8;     // K staging assignment
    ushort_t* pw = Ps[wave];

    for (int t = 0; t < S_/64; t++) {
        const int kbase = t * 64;
        __syncthreads();                              // prev-iter reads done
        // ---- stage K tile [64][72], coalesced b128 global reads ----
        {
            const ushort_t* kp = k + headbase + (size_t)(kbase + kr) * RS + kc;
            short8 k0 = *(const short8*)kp;
            short8 k1 = *(const short8*)(kp + (size_t)32 * RS);
            *(short8*)&Ks[kr*72 + kc]        = k0;
            *(short8*)&Ks[(kr + 32)*72 + kc] = k1;
        }
        // ---- stage V^T: lane reads column d=lane (128B coalesced per j) ----
        {
            const ushort_t* vp = v + headbase + (size_t)(kbase + wave*16) * RS + lane;
            short8 w0, w1;
            #pragma unroll
            for (int j = 0; j < 8; j++) {
                ((ushort_t*)&w0)[j] = vp[(size_t)j * RS];
                ((ushort_t*)&w1)[j] = vp[(size_t)(j + 8) * RS];
            }
            *(short8*)&Vt[lane*72 + wave*16]     = w0;
            *(short8*)&Vt[lane*72 + wave*16 + 8] = w1;
        }
        __syncthreads();

        // ---- S = (Q K^T) * 0.125 ; S[q=(lg*4+r)][kcol=lr+16*nt] ----
        floatx4 sacc[4];
        #pragma unroll
        for (int nt = 0; nt < 4; nt++) sacc[nt] = (floatx4)(0.f);
        #pragma unroll
        for (int nt = 0; nt < 4; nt++) {
            short8 b0 = *(const short8*)&Ks[(lr + nt*16)*72 + lg*8];
            sacc[nt] = __builtin_amdgcn_mfma_f32_16x16x32_bf16(qf0, b0, sacc[nt], 0, 0, 0);
            short8 b1 = *(const short8*)&Ks[(lr + nt*16)*72 + 32 + lg*8];
            sacc[nt] = __builtin_amdgcn_mfma_f32_16x16x32_bf16(qf1, b1, sacc[nt], 0, 0, 0);
        }

        // ---- online softmax: row reduce across the 16-lane column group ----
        float alpha[4];
        #pragma unroll
        for (int r = 0; r < 4; r++) {
            float rm = -1e30f;
            #pragma unroll
            for (int nt = 0; nt < 4; nt++) { sacc[nt][r] *= 0.125f; rm = fmaxf(rm, sacc[nt][r]); }
            #pragma unroll
            for (int o = 1; o < 16; o <<= 1) rm = fmaxf(rm, __shfl_xor(rm, o, 64));
            float nm = fmaxf(m_i[r], rm);
            alpha[r] = __expf(m_i[r] - nm);
            m_i[r] = nm;
            float rs = 0.f;
            #pragma unroll
            for (int nt = 0; nt < 4; nt++) { sacc[nt][r] = __expf(sacc[nt][r] - nm); rs += sacc[nt][r]; }
            #pragma unroll
            for (int o = 1; o < 16; o <<= 1) rs += __shfl_xor(rs, o, 64);
            l_i[r] = l_i[r] * alpha[r] + rs;
        }

        // ---- P -> per-wave LDS (bf16), reshaping for A-fragment reads ----
        #pragma unroll
        for (int nt = 0; nt < 4; nt++)
            #pragma unroll
            for (int r = 0; r < 4; r++)
                pw[(lg*4 + r)*72 + lr + nt*16] = f2bf(sacc[nt][r]);

        // ---- O rescale, then O += P V ----
        #pragma unroll
        for (int nt = 0; nt < 4; nt++)
            #pragma unroll
            for (int r = 0; r < 4; r++)
                O[nt][r] *= alpha[r];

        asm volatile("s_waitcnt lgkmcnt(0)" ::: "memory");  // P writes visible (same wave)

        #pragma unroll
        for (int kh = 0; kh < 2; kh++) {
            short8 pa = *(const short8*)&pw[lr*72 + kh*32 + lg*8];
            #pragma unroll
            for (int nt = 0; nt < 4; nt++) {
                short8 bv = *(const short8*)&Vt[(lr + nt*16)*72 + kh*32 + lg*8];
                O[nt] = __builtin_amdgcn_mfma_f32_16x16x32_bf16(pa, bv, O[nt], 0, 0, 0);
            }
        }
    }

    // ---- epilogue: O/l via per-wave LDS transpose for coalesced stores ----
    #pragma unroll
    for (int r = 0; r < 4; r++) {
        float inv = 1.f / l_i[r];
        #pragma unroll
        for (int nt = 0; nt < 4; nt++)
            pw[(lg*4 + r)*72 + lr + nt*16] = f2bf(O[nt][r] * inv);
    }
    asm volatile("s_waitcnt lgkmcnt(0)" ::: "memory");
    {
        const int row = lane >> 2, c0 = (lane & 3) * 16;
        short8 o0 = *(const short8*)&pw[row*72 + c0];
        short8 o1 = *(const short8*)&pw[row*72 + c0 + 8];
        ushort_t* gp = ctx + headbase + (size_t)(s0 + wave*16 + row) * RS + c0;
        *(short8*)gp       = o0;
        *(short8*)(gp + 8) = o1;
    }
}

extern "C" void kernel_launch(void* const* d_in, const int* in_sizes, int n_in,
                              void* d_out, int out_size, void* d_ws, size_t ws_size,
                              hipStream_t stream)
{
    const float* x    = (const float*)d_in[0];
    const float* wq1  = (const float*)d_in[2];
    const float* bq1  = (const float*)d_in[3];
    const float* wq2  = (const float*)d_in[4];
    const float* bq2  = (const float*)d_in[5];
    const float* wk1  = (const float*)d_in[6];
    const float* bk1  = (const float*)d_in[7];
    const float* wk2  = (const float*)d_in[8];
    const float* bk2  = (const float*)d_in[9];
    const float* wv1  = (const float*)d_in[10];
    const float* bv1  = (const float*)d_in[11];
    const float* wv2  = (const float*)d_in[12];
    const float* bv2  = (const float*)d_in[13];
    const float* wo   = (const float*)d_in[14];
    const float* bo   = (const float*)d_in[15];
    const float* ln1g = (const float*)d_in[16];
    const float* ln1b = (const float*)d_in[17];
    const float* ln2g = (const float*)d_in[18];
    const float* ln2b = (const float*)d_in[19];
    const float* gw   = (const float*)d_in[20];
    const float* gb   = (const float*)d_in[21];
    const float* ew1  = (const float*)d_in[22];
    const float* eb1  = (const float*)d_in[23];
    const float* ew2  = (const float*)d_in[24];
    const float* eb2  = (const float*)d_in[25];
    const float* ew3  = (const float*)d_in[26];
    const float* eb3  = (const float*)d_in[27];
    float* out = (float*)d_out;

    char* w = (char*)d_ws;
    ushort_t* wq1t = (ushort_t*)w; w += (size_t)D_*D_*2;
    ushort_t* wq2t = (ushort_t*)w; w += (size_t)D_*D_*2;
    ushort_t* wk1t = (ushort_t*)w; w += (size_t)D_*D_*2;
    ushort_t* wk2t = (ushort_t*)w; w += (size_t)D_*D_*2;
    ushort_t* wv1t = (ushort_t*)w; w += (size_t)D_*D_*2;
    ushort_t* wv2t = (ushort_t*)w; w += (size_t)D_*D_*2;
    ushort_t* wot  = (ushort_t*)w; w += (size_t)D_*D_*2;
    ushort_t* e1t  = (ushort_t*)w; w += (size_t)D_*F_*2;
    ushort_t* e3t  = (ushort_t*)w; w += (size_t)D_*F_*2;
    ushort_t* e2t  = (ushort_t*)w; w += (size_t)D_*F_*2;
    ushort_t* x2h  = (ushort_t*)w; w += (size_t)NTOK*D_*2;
    ushort_t* qh   = (ushort_t*)w; w += (size_t)NTOK*D_*2;
    ushort_t* kh   = (ushort_t*)w; w += (size_t)NTOK*D_*2;
    ushort_t* vh   = (ushort_t*)w; w += (size_t)NTOK*D_*2;
    ushort_t* ctxh = (ushort_t*)w; w += (size_t)NTOK*D_*2;
    ushort_t* x2bh = (ushort_t*)w; w += (size_t)NTOK*D_*2;
    ushort_t* hAh  = (ushort_t*)w; w += (size_t)NTOK*F_*2;
    int*      cnts = (int*)w;      w += 256;
    int*      idxl = (int*)w;      w += (size_t)E_*NTOK*4;
    float*    wgtl = (float*)w;    w += (size_t)E_*NTOK*4;
    int*      tope = (int*)w;      w += (size_t)NTOK*4;
    float2*   topw = (float2*)w;   w += (size_t)NTOK*8;

    dim3 blk(256);

    W7 p7;
    p7.s[0]=wq1; p7.d[0]=wq1t; p7.s[1]=wq2; p7.d[1]=wq2t;
    p7.s[2]=wk1; p7.d[2]=wk1t; p7.s[3]=wk2; p7.d[3]=wk2t;
    p7.s[4]=wv1; p7.d[4]=wv1t; p7.s[5]=wv2; p7.d[5]=wv2t;
    p7.s[6]=wo;  p7.d[6]=wot;
    transpose7<<<dim3(32,32,7), blk, 0, stream>>>(p7, D_, D_);

    // --- pre-norm attention ---
    ln_kernel<<<NTOK, blk, 0, stream>>>(x, ln1g, ln1b, x2h);
    dim3 gDD(D_/128, NTOK/128);
    mgemm<3><<<gDD, blk, 0, stream>>>(x2h, wq1t, bq1, wq2t, bq2, nullptr, qh, NTOK, D_, D_);
    mgemm<3><<<gDD, blk, 0, stream>>>(x2h, wk1t, bk1, wk2t, bk2, nullptr, kh, NTOK, D_, D_);
    mgemm<3><<<gDD, blk, 0, stream>>>(x2h, wv1t, bv1, wv2t, bv2, nullptr, vh, NTOK, D_, D_);
    fattn_kernel<<<B_ * H_ * (S_/64), blk, 0, stream>>>(qh, kh, vh, ctxh);
    mgemm<1><<<gDD, blk, 0, stream>>>(ctxh, wot, bo, nullptr, nullptr, x, out, NTOK, D_, D_);

    // --- pre-norm MoE SwiGLU FFN (top-2 sparse), gate fused into LN ---
    ln_gate_kernel<<<NTOK, blk, 0, stream>>>(out, ln2g, ln2b, x2bh, gw, gb,
                                             tope, topw);
    build_lists<<<dim3(E_), blk, 0, stream>>>(tope, topw, cnts, idxl, wgtl);

    dim3 gFD(F_/128, NTOK/128);
    for (int e = 0; e < E_; e++) {
        transpose_cvt<<<dim3(F_/32, D_/32, 2), blk, 0, stream>>>(
            ew1 + (size_t)e*D_*F_, e1t, ew3 + (size_t)e*D_*F_, e3t, D_, F_);
        transpose_cvt<<<dim3(D_/32, F_/32, 1), blk, 0, stream>>>(
            ew2 + (size_t)e*F_*D_, e2t, nullptr, nullptr, F_, D_);
        mgemm_up<<<gFD, blk, 0, stream>>>(x2bh, idxl + (size_t)e*NTOK, cnts, e,
                                          e1t, eb1 + (size_t)e*F_, e3t, eb3 + (size_t)e*F_,
                                          hAh, F_, D_);
        mgemm_down<<<gDD, blk, 0, stream>>>(hAh, idxl + (size_t)e*NTOK, wgtl + (size_t)e*NTOK,
                                            cnts, e, e2t, eb2 + (size_t)e*D_, out, D_, F_);
    }
}

// Round 5
// 867.355 us; speedup vs baseline: 2.0559x; 1.6003x over previous
//
#include <hip/hip_runtime.h>
#include <math.h>

#define B_ 4
#define S_ 1024
#define D_ 1024
#define F_ 2048
#define H_ 16
#define E_ 8
#define DK_ 64
#define NTOK (B_*S_)

typedef unsigned short ushort_t;
typedef __attribute__((ext_vector_type(8))) short short8;
typedef __attribute__((ext_vector_type(4))) float floatx4;

// ---- bf16 helpers (RNE) ----
__device__ __forceinline__ ushort_t f2bf(float f) {
    unsigned u = __float_as_uint(f);
    unsigned r = (u + 0x7fffu + ((u >> 16) & 1u)) >> 16;
    return (ushort_t)r;
}
__device__ __forceinline__ float bf2f(ushort_t h) {
    return __uint_as_float(((unsigned)h) << 16);
}

// ---- async global->LDS 16B ----
__device__ __forceinline__ void gload16(const void* g, void* l) {
    __builtin_amdgcn_global_load_lds(
        (const __attribute__((address_space(1))) unsigned*)g,
        (__attribute__((address_space(3))) unsigned*)l, 16, 0, 0);
}

// ---------------- block reductions (256 threads = 4 waves) ----------------
__device__ __forceinline__ float blockReduceSum256(float v, volatile float* sred) {
    int tid = threadIdx.x;
    #pragma unroll
    for (int o = 32; o > 0; o >>= 1) v += __shfl_down(v, o, 64);
    __syncthreads();
    if ((tid & 63) == 0) sred[tid >> 6] = v;
    __syncthreads();
    return sred[0] + sred[1] + sred[2] + sred[3];
}

// ---------------- LayerNorm: one block per row; writes bf16 ---------------
__global__ __launch_bounds__(256)
void ln_kernel(const float* __restrict__ x, const float* __restrict__ g,
               const float* __restrict__ b, ushort_t* __restrict__ yh) {
    __shared__ float sred[4];
    int row = blockIdx.x;
    int tid = threadIdx.x;
    const float* xr = x + (size_t)row * D_;
    float v[4];
    float s = 0.f;
    #pragma unroll
    for (int i = 0; i < 4; i++) { v[i] = xr[tid + 256*i]; s += v[i]; }
    float mean = blockReduceSum256(s, sred) * (1.f / D_);
    float s2 = 0.f;
    #pragma unroll
    for (int i = 0; i < 4; i++) { float d = v[i] - mean; s2 += d * d; }
    float var = blockReduceSum256(s2, sred) * (1.f / D_);
    float rstd = rsqrtf(var + 1e-5f);
    #pragma unroll
    for (int i = 0; i < 4; i++) {
        int c = tid + 256*i;
        float r = (v[i] - mean) * rstd * g[c] + b[c];
        yh[(size_t)row * D_ + c] = f2bf(r);
    }
}

// ------- LayerNorm fused with MoE gate (softmax + top-2, NO atomics) ------
__global__ __launch_bounds__(256)
void ln_gate_kernel(const float* __restrict__ x, const float* __restrict__ g,
                    const float* __restrict__ b, ushort_t* __restrict__ yh,
                    const float* __restrict__ gw, const float* __restrict__ gb,
                    int* __restrict__ tope, float2* __restrict__ topw) {
    __shared__ float sred[4];
    __shared__ float sgate[4][E_];
    int row = blockIdx.x;
    int tid = threadIdx.x;
    const float* xr = x + (size_t)row * D_;
    float v[4];
    float s = 0.f;
    #pragma unroll
    for (int i = 0; i < 4; i++) { v[i] = xr[tid + 256*i]; s += v[i]; }
    float mean = blockReduceSum256(s, sred) * (1.f / D_);
    float s2 = 0.f;
    #pragma unroll
    for (int i = 0; i < 4; i++) { float d = v[i] - mean; s2 += d * d; }
    float var = blockReduceSum256(s2, sred) * (1.f / D_);
    float rstd = rsqrtf(var + 1e-5f);

    float p[E_];
    #pragma unroll
    for (int e = 0; e < E_; e++) p[e] = 0.f;
    #pragma unroll
    for (int i = 0; i < 4; i++) {
        int c = tid + 256*i;
        float r = (v[i] - mean) * rstd * g[c] + b[c];
        yh[(size_t)row * D_ + c] = f2bf(r);
        const float* gwr = gw + (size_t)c * E_;
        #pragma unroll
        for (int e = 0; e < E_; e++) p[e] += r * gwr[e];
    }
    #pragma unroll
    for (int o = 32; o > 0; o >>= 1)
        #pragma unroll
        for (int e = 0; e < E_; e++) p[e] += __shfl_down(p[e], o, 64);
    __syncthreads();
    if ((tid & 63) == 0) {
        #pragma unroll
        for (int e = 0; e < E_; e++) sgate[tid >> 6][e] = p[e];
    }
    __syncthreads();
    if (tid == 0) {
        float q[E_];
        float mx = -1e30f;
        #pragma unroll
        for (int e = 0; e < E_; e++) {
            q[e] = sgate[0][e] + sgate[1][e] + sgate[2][e] + sgate[3][e] + gb[e];
            mx = fmaxf(mx, q[e]);
        }
        float sum = 0.f;
        #pragma unroll
        for (int e = 0; e < E_; e++) { q[e] = expf(q[e] - mx); sum += q[e]; }
        #pragma unroll
        for (int e = 0; e < E_; e++) q[e] /= sum;
        int i1 = 0;
        #pragma unroll
        for (int e = 1; e < E_; e++) if (q[e] > q[i1]) i1 = e;
        int i2 = (i1 == 0) ? 1 : 0;
        #pragma unroll
        for (int e = 0; e < E_; e++) if (e != i2 && e != i1 && q[e] > q[i2]) i2 = e;
        float denom = q[i1] + q[i2] + 1e-6f;
        tope[row] = i1 | (i2 << 8);
        topw[row] = make_float2(q[i1] / denom, q[i2] / denom);
    }
}

// ------- build per-expert token lists + flat offsets (no atomics) ---------
__global__ __launch_bounds__(256)
void build_lists(const int* __restrict__ tope, const float2* __restrict__ topw,
                 int* __restrict__ counts, int* __restrict__ offs,
                 int* __restrict__ idxl, float* __restrict__ wgtl)
{
    const int e = blockIdx.x;
    const int tid = threadIdx.x;
    const int lane = tid & 63, wv = tid >> 6;
    __shared__ int wsum[4];
    __shared__ int sbase;
    __shared__ int ctot[4][E_];
    if (tid == 0) sbase = 0;
    __syncthreads();
    int* il = idxl + (size_t)e * NTOK;
    float* wl = wgtl + (size_t)e * NTOK;
    int c8[E_];
    #pragma unroll
    for (int i = 0; i < E_; i++) c8[i] = 0;
    for (int t0 = 0; t0 < NTOK; t0 += 256) {
        int t = t0 + tid;
        int pk = tope[t];
        int i1 = pk & 255, i2 = (pk >> 8) & 255;
        #pragma unroll
        for (int i = 0; i < E_; i++) c8[i] += (i1 == i) + (i2 == i);
        bool m = (i1 == e) || (i2 == e);
        float2 wp = topw[t];
        float w = (i1 == e) ? wp.x : wp.y;
        unsigned long long mask = __ballot(m);
        int wpos = __popcll(mask & ((1ull << lane) - 1ull));
        int wcnt = __popcll(mask);
        if (lane == 0) wsum[wv] = wcnt;
        __syncthreads();
        int base = sbase;
        int pre = 0;
        #pragma unroll
        for (int i = 0; i < 4; i++) if (i < wv) pre += wsum[i];
        if (m) { il[base + pre + wpos] = t; wl[base + pre + wpos] = w; }
        __syncthreads();
        if (tid == 0) sbase = base + wsum[0] + wsum[1] + wsum[2] + wsum[3];
    }
    #pragma unroll
    for (int i = 0; i < E_; i++)
        #pragma unroll
        for (int o = 32; o > 0; o >>= 1) c8[i] += __shfl_down(c8[i], o, 64);
    if (lane == 0) {
        #pragma unroll
        for (int i = 0; i < E_; i++) ctot[wv][i] = c8[i];
    }
    __syncthreads();
    if (tid == 0) {
        int off = 0;
        for (int i = 0; i < e; i++)
            off += ctot[0][i] + ctot[1][i] + ctot[2][i] + ctot[3][i];
        offs[e] = off;
        counts[e] = sbase;
    }
}

// ------- attention weight transposes: 7 matrices, one dispatch ------------
struct W7 { const float* s[7]; ushort_t* d[7]; };
__global__ __launch_bounds__(256)
void transpose7(W7 p, int R, int C)
{
    const float* s = p.s[blockIdx.z];
    ushort_t* d = p.d[blockIdx.z];
    __shared__ float t[32][33];
    int r0 = blockIdx.y * 32, c0 = blockIdx.x * 32;
    int lr = threadIdx.x >> 3, lc = (threadIdx.x & 7) * 4;
    float4 v = *(const float4*)(s + (size_t)(r0 + lr) * C + c0 + lc);
    t[lr][lc+0] = v.x; t[lr][lc+1] = v.y; t[lr][lc+2] = v.z; t[lr][lc+3] = v.w;
    __syncthreads();
    ushort4 o;
    o.x = f2bf(t[lc+0][lr]); o.y = f2bf(t[lc+1][lr]);
    o.z = f2bf(t[lc+2][lr]); o.w = f2bf(t[lc+3][lr]);
    *(ushort4*)(d + (size_t)(c0 + lr) * R + r0 + lc) = o;
}

// ------- expert up-proj weight transposes (ew1 & ew3), one dispatch -------
// z = e*2 + which; src [D,F] f32 -> dst [F,D] bf16. grid (F/32, D/32, 16).
__global__ __launch_bounds__(256)
void transpose_e13(const float* __restrict__ ew1, const float* __restrict__ ew3,
                   ushort_t* __restrict__ e1t, ushort_t* __restrict__ e3t)
{
    const int z = blockIdx.z;
    const int e = z >> 1, which = z & 1;
    const float* s = (which ? ew3 : ew1) + (size_t)e * D_ * F_;
    ushort_t* d = (which ? e3t : e1t) + (size_t)e * D_ * F_;
    const int R = D_, C = F_;
    int r0 = blockIdx.y * 32, c0 = blockIdx.x * 32;
    __shared__ float t[32][33];
    int lr = threadIdx.x >> 3, lc = (threadIdx.x & 7) * 4;
    float4 v = *(const float4*)(s + (size_t)(r0 + lr) * C + c0 + lc);
    t[lr][lc+0] = v.x; t[lr][lc+1] = v.y; t[lr][lc+2] = v.z; t[lr][lc+3] = v.w;
    __syncthreads();
    ushort4 o;
    o.x = f2bf(t[lc+0][lr]); o.y = f2bf(t[lc+1][lr]);
    o.z = f2bf(t[lc+2][lr]); o.w = f2bf(t[lc+3][lr]);
    *(ushort4*)(d + (size_t)(c0 + lr) * R + r0 + lc) = o;
}

// ------- expert down-proj weight transpose (ew2), one dispatch ------------
// z = e; src [F,D] f32 -> dst [D,F] bf16. grid (D/32, F/32, 8).
__global__ __launch_bounds__(256)
void transpose_e2(const float* __restrict__ ew2, ushort_t* __restrict__ e2t)
{
    const int e = blockIdx.z;
    const float* s = ew2 + (size_t)e * F_ * D_;
    ushort_t* d = e2t + (size_t)e * F_ * D_;
    const int R = F_, C = D_;
    int r0 = blockIdx.y * 32, c0 = blockIdx.x * 32;
    __shared__ float t[32][33];
    int lr = threadIdx.x >> 3, lc = (threadIdx.x & 7) * 4;
    float4 v = *(const float4*)(s + (size_t)(r0 + lr) * C + c0 + lc);
    t[lr][lc+0] = v.x; t[lr][lc+1] = v.y; t[lr][lc+2] = v.z; t[lr][lc+3] = v.w;
    __syncthreads();
    ushort4 o;
    o.x = f2bf(t[lc+0][lr]); o.y = f2bf(t[lc+1][lr]);
    o.z = f2bf(t[lc+2][lr]); o.w = f2bf(t[lc+3][lr]);
    *(ushort4*)(d + (size_t)(c0 + lr) * R + r0 + lc) = o;
}

// ---------------- MFMA bf16 GEMM: C = A[M,K] @ B^T (B stored [N,K]) ------
// 128x128 tile, BK=32, 256 thr (2x2 waves of 64x64), 16x16x32 MFMA.
// Cf = acc + bias1 + R  (f32 out)
__global__ __launch_bounds__(256)
void mgemm_res(const ushort_t* __restrict__ A, const ushort_t* __restrict__ B1,
               const float* __restrict__ bias1, const float* __restrict__ R,
               float* __restrict__ Cv, int M, int N, int K)
{
    __shared__ __align__(16) ushort_t As [128*32];
    __shared__ __align__(16) ushort_t Bs1[128*32];

    int tid = threadIdx.x;
    int m0 = blockIdx.y * 128, n0 = blockIdx.x * 128;
    int trow = tid >> 2;
    int tcol = (tid & 3) * 8;
    const ushort_t* gA  = A  + (size_t)(m0 + trow) * K + tcol;
    const ushort_t* gB1 = B1 + (size_t)(n0 + trow) * K + tcol;
    ushort_t* lA  = &As [trow*32 + tcol];
    ushort_t* lB1 = &Bs1[trow*32 + tcol];

    int wave = tid >> 6, lane = tid & 63;
    int wm = (wave >> 1) * 64, wn = (wave & 1) * 64;
    int fr = lane & 15, fk = (lane >> 4) * 8;
    const ushort_t* pa  = &As [(wm + fr)*32 + fk];
    const ushort_t* pb1 = &Bs1[(wn + fr)*32 + fk];

    floatx4 acc1[4][4];
    #pragma unroll
    for (int i = 0; i < 4; i++)
        #pragma unroll
        for (int j = 0; j < 4; j++) acc1[i][j] = (floatx4)(0.f);

    for (int k0 = 0; k0 < K; k0 += 32) {
        gload16(gA  + k0,            lA);
        gload16(gA  + (size_t)64*K + k0, lA  + 64*32);
        gload16(gB1 + k0,            lB1);
        gload16(gB1 + (size_t)64*K + k0, lB1 + 64*32);
        __syncthreads();

        short8 a[4];
        #pragma unroll
        for (int mt = 0; mt < 4; mt++) a[mt] = *(const short8*)(pa + mt*16*32);
        short8 b[4];
        #pragma unroll
        for (int nt = 0; nt < 4; nt++) b[nt] = *(const short8*)(pb1 + nt*16*32);
        #pragma unroll
        for (int mt = 0; mt < 4; mt++)
            #pragma unroll
            for (int nt = 0; nt < 4; nt++)
                acc1[mt][nt] = __builtin_amdgcn_mfma_f32_16x16x32_bf16(
                    a[mt], b[nt], acc1[mt][nt], 0, 0, 0);
        __syncthreads();
    }

    int ecol0 = n0 + wn + (lane & 15);
    int erow0 = m0 + wm + (lane >> 4) * 4;
    #pragma unroll
    for (int mt = 0; mt < 4; mt++) {
        #pragma unroll
        for (int nt = 0; nt < 4; nt++) {
            int col = ecol0 + nt * 16;
            #pragma unroll
            for (int r = 0; r < 4; r++) {
                int row = erow0 + mt * 16 + r;
                size_t idx = (size_t)row * N + col;
                Cv[idx] = acc1[mt][nt][r] + bias1[col] + R[idx];
            }
        }
    }
}

// ---------------- fused Q/K/V dual-B SwiGLU projections (grid.z = 0..2) ---
struct QKV {
    const ushort_t* B1[3]; const ushort_t* B2[3];
    const float* bias1[3]; const float* bias2[3];
    ushort_t* C[3];
};
__global__ __launch_bounds__(256)
void mgemm_qkv(const ushort_t* __restrict__ A, QKV p)
{
    const int z = blockIdx.z;
    const ushort_t* B1 = p.B1[z];
    const ushort_t* B2 = p.B2[z];
    const float* bias1 = p.bias1[z];
    const float* bias2 = p.bias2[z];
    ushort_t* C = p.C[z];
    const int N = D_, K = D_;

    __shared__ __align__(16) ushort_t As [128*32];
    __shared__ __align__(16) ushort_t Bs1[128*32];
    __shared__ __align__(16) ushort_t Bs2[128*32];

    int tid = threadIdx.x;
    int m0 = blockIdx.y * 128, n0 = blockIdx.x * 128;
    int trow = tid >> 2;
    int tcol = (tid & 3) * 8;
    const ushort_t* gA  = A  + (size_t)(m0 + trow) * K + tcol;
    const ushort_t* gB1 = B1 + (size_t)(n0 + trow) * K + tcol;
    const ushort_t* gB2 = B2 + (size_t)(n0 + trow) * K + tcol;
    ushort_t* lA  = &As [trow*32 + tcol];
    ushort_t* lB1 = &Bs1[trow*32 + tcol];
    ushort_t* lB2 = &Bs2[trow*32 + tcol];

    int wave = tid >> 6, lane = tid & 63;
    int wm = (wave >> 1) * 64, wn = (wave & 1) * 64;
    int fr = lane & 15, fk = (lane >> 4) * 8;
    const ushort_t* pa  = &As [(wm + fr)*32 + fk];
    const ushort_t* pb1 = &Bs1[(wn + fr)*32 + fk];
    const ushort_t* pb2 = &Bs2[(wn + fr)*32 + fk];

    floatx4 acc1[4][4], acc2[4][4];
    #pragma unroll
    for (int i = 0; i < 4; i++)
        #pragma unroll
        for (int j = 0; j < 4; j++) { acc1[i][j] = (floatx4)(0.f); acc2[i][j] = (floatx4)(0.f); }

    for (int k0 = 0; k0 < K; k0 += 32) {
        gload16(gA  + k0,            lA);
        gload16(gA  + (size_t)64*K + k0, lA  + 64*32);
        gload16(gB1 + k0,            lB1);
        gload16(gB1 + (size_t)64*K + k0, lB1 + 64*32);
        gload16(gB2 + k0,            lB2);
        gload16(gB2 + (size_t)64*K + k0, lB2 + 64*32);
        __syncthreads();

        short8 a[4];
        #pragma unroll
        for (int mt = 0; mt < 4; mt++) a[mt] = *(const short8*)(pa + mt*16*32);
        {
            short8 b[4];
            #pragma unroll
            for (int nt = 0; nt < 4; nt++) b[nt] = *(const short8*)(pb1 + nt*16*32);
            #pragma unroll
            for (int mt = 0; mt < 4; mt++)
                #pragma unroll
                for (int nt = 0; nt < 4; nt++)
                    acc1[mt][nt] = __builtin_amdgcn_mfma_f32_16x16x32_bf16(
                        a[mt], b[nt], acc1[mt][nt], 0, 0, 0);
        }
        {
            short8 b[4];
            #pragma unroll
            for (int nt = 0; nt < 4; nt++) b[nt] = *(const short8*)(pb2 + nt*16*32);
            #pragma unroll
            for (int mt = 0; mt < 4; mt++)
                #pragma unroll
                for (int nt = 0; nt < 4; nt++)
                    acc2[mt][nt] = __builtin_amdgcn_mfma_f32_16x16x32_bf16(
                        a[mt], b[nt], acc2[mt][nt], 0, 0, 0);
        }
        __syncthreads();
    }

    int ecol0 = n0 + wn + (lane & 15);
    int erow0 = m0 + wm + (lane >> 4) * 4;
    #pragma unroll
    for (int mt = 0; mt < 4; mt++) {
        #pragma unroll
        for (int nt = 0; nt < 4; nt++) {
            int col = ecol0 + nt * 16;
            #pragma unroll
            for (int r = 0; r < 4; r++) {
                int row = erow0 + mt * 16 + r;
                float x1 = acc1[mt][nt][r] + bias1[col];
                float x2 = acc2[mt][nt][r] + bias2[col];
                float h = x1 / (1.f + __expf(-x1)) * x2;
                C[(size_t)row * N + col] = f2bf(h);
            }
        }
    }
}

// ------- fused MoE up-proj over all experts (grid.z = expert) -------------
// A = x2 bf16 [NTOK,D]; C flat-compact [offs[e]+row, F] bf16.
// Epilogue writes GUARDED by row < cnt (compact regions are exactly cnt rows).
__global__ __launch_bounds__(256)
void mgemm_up_all(const ushort_t* __restrict__ A, const int* __restrict__ idxl_all,
                  const int* __restrict__ counts, const int* __restrict__ offs,
                  const ushort_t* __restrict__ B1a, const float* __restrict__ b1a,
                  const ushort_t* __restrict__ B2a, const float* __restrict__ b2a,
                  ushort_t* __restrict__ Call)
{
    const int e = blockIdx.z;
    int cnt = counts[e];
    int m0 = blockIdx.y * 128;
    if (m0 >= cnt) return;
    const int N = F_, K = D_;
    const int* idxl = idxl_all + (size_t)e * NTOK;
    const ushort_t* B1 = B1a + (size_t)e * D_ * F_;
    const ushort_t* B2 = B2a + (size_t)e * D_ * F_;
    const float* bias1 = b1a + (size_t)e * F_;
    const float* bias2 = b2a + (size_t)e * F_;
    ushort_t* C = Call + (size_t)offs[e] * F_;

    __shared__ __align__(16) ushort_t As [128*32];
    __shared__ __align__(16) ushort_t Bs1[128*32];
    __shared__ __align__(16) ushort_t Bs2[128*32];

    int tid = threadIdx.x;
    int n0 = blockIdx.x * 128;
    int trow = tid >> 2;
    int tcol = (tid & 3) * 8;
    int r0 = m0 + trow, r1 = m0 + 64 + trow;
    int t0 = (r0 < cnt) ? idxl[r0] : 0;
    int t1 = (r1 < cnt) ? idxl[r1] : 0;
    const ushort_t* gA0 = A + (size_t)t0 * K + tcol;
    const ushort_t* gA1 = A + (size_t)t1 * K + tcol;
    const ushort_t* gB1 = B1 + (size_t)(n0 + trow) * K + tcol;
    const ushort_t* gB2 = B2 + (size_t)(n0 + trow) * K + tcol;
    ushort_t* lA  = &As [trow*32 + tcol];
    ushort_t* lB1 = &Bs1[trow*32 + tcol];
    ushort_t* lB2 = &Bs2[trow*32 + tcol];

    int wave = tid >> 6, lane = tid & 63;
    int wm = (wave >> 1) * 64, wn = (wave & 1) * 64;
    int fr = lane & 15, fk = (lane >> 4) * 8;
    const ushort_t* pa  = &As [(wm + fr)*32 + fk];
    const ushort_t* pb1 = &Bs1[(wn + fr)*32 + fk];
    const ushort_t* pb2 = &Bs2[(wn + fr)*32 + fk];

    floatx4 acc1[4][4], acc2[4][4];
    #pragma unroll
    for (int i = 0; i < 4; i++)
        #pragma unroll
        for (int j = 0; j < 4; j++) { acc1[i][j] = (floatx4)(0.f); acc2[i][j] = (floatx4)(0.f); }

    for (int k0 = 0; k0 < K; k0 += 32) {
        gload16(gA0 + k0, lA);
        gload16(gA1 + k0, lA + 64*32);
        gload16(gB1 + k0, lB1);
        gload16(gB1 + (size_t)64*K + k0, lB1 + 64*32);
        gload16(gB2 + k0, lB2);
        gload16(gB2 + (size_t)64*K + k0, lB2 + 64*32);
        __syncthreads();

        short8 a[4];
        #pragma unroll
        for (int mt = 0; mt < 4; mt++) a[mt] = *(const short8*)(pa + mt*16*32);
        {
            short8 b[4];
            #pragma unroll
            for (int nt = 0; nt < 4; nt++) b[nt] = *(const short8*)(pb1 + nt*16*32);
            #pragma unroll
            for (int mt = 0; mt < 4; mt++)
                #pragma unroll
                for (int nt = 0; nt < 4; nt++)
                    acc1[mt][nt] = __builtin_amdgcn_mfma_f32_16x16x32_bf16(
                        a[mt], b[nt], acc1[mt][nt], 0, 0, 0);
        }
        {
            short8 b[4];
            #pragma unroll
            for (int nt = 0; nt < 4; nt++) b[nt] = *(const short8*)(pb2 + nt*16*32);
            #pragma unroll
            for (int mt = 0; mt < 4; mt++)
                #pragma unroll
                for (int nt = 0; nt < 4; nt++)
                    acc2[mt][nt] = __builtin_amdgcn_mfma_f32_16x16x32_bf16(
                        a[mt], b[nt], acc2[mt][nt], 0, 0, 0);
        }
        __syncthreads();
    }

    int ecol0 = n0 + wn + (lane & 15);
    int erow0 = m0 + wm + (lane >> 4) * 4;
    #pragma unroll
    for (int mt = 0; mt < 4; mt++) {
        #pragma unroll
        for (int nt = 0; nt < 4; nt++) {
            int col = ecol0 + nt * 16;
            #pragma unroll
            for (int r = 0; r < 4; r++) {
                int row = erow0 + mt * 16 + r;
                if (row < cnt) {
                    float x1 = acc1[mt][nt][r] + bias1[col];
                    float x2 = acc2[mt][nt][r] + bias2[col];
                    float h = x1 / (1.f + __expf(-x1)) * x2;
                    C[(size_t)row * N + col] = f2bf(h);
                }
            }
        }
    }
}

// ------- fused MoE down-proj over all experts; atomic scatter-add ---------
// Reads of rows >= cnt hit the 128-row pad at end of hAh (garbage, masked).
__global__ __launch_bounds__(256)
void mgemm_down_all(const ushort_t* __restrict__ hA, const int* __restrict__ idxl_all,
                    const float* __restrict__ wgtl_all, const int* __restrict__ counts,
                    const int* __restrict__ offs, const ushort_t* __restrict__ B1a,
                    const float* __restrict__ b1a, float* __restrict__ out)
{
    const int e = blockIdx.z;
    int cnt = counts[e];
    int m0 = blockIdx.y * 128;
    if (m0 >= cnt) return;
    const int N = D_, K = F_;
    const int* idxl = idxl_all + (size_t)e * NTOK;
    const float* wgtl = wgtl_all + (size_t)e * NTOK;
    const ushort_t* A = hA + (size_t)offs[e] * F_;
    const ushort_t* B1 = B1a + (size_t)e * F_ * D_;
    const float* bias1 = b1a + (size_t)e * D_;

    __shared__ __align__(16) ushort_t As [128*32];
    __shared__ __align__(16) ushort_t Bs1[128*32];

    int tid = threadIdx.x;
    int n0 = blockIdx.x * 128;
    int trow = tid >> 2;
    int tcol = (tid & 3) * 8;
    const ushort_t* gA  = A  + (size_t)(m0 + trow) * K + tcol;
    const ushort_t* gB1 = B1 + (size_t)(n0 + trow) * K + tcol;
    ushort_t* lA  = &As [trow*32 + tcol];
    ushort_t* lB1 = &Bs1[trow*32 + tcol];

    int wave = tid >> 6, lane = tid & 63;
    int wm = (wave >> 1) * 64, wn = (wave & 1) * 64;
    int fr = lane & 15, fk = (lane >> 4) * 8;
    const ushort_t* pa  = &As [(wm + fr)*32 + fk];
    const ushort_t* pb1 = &Bs1[(wn + fr)*32 + fk];

    floatx4 acc1[4][4];
    #pragma unroll
    for (int i = 0; i < 4; i++)
        #pragma unroll
        for (int j = 0; j < 4; j++) acc1[i][j] = (floatx4)(0.f);

    for (int k0 = 0; k0 < K; k0 += 32) {
        gload16(gA + k0,             lA);
        gload16(gA + (size_t)64*K + k0, lA + 64*32);
        gload16(gB1 + k0,            lB1);
        gload16(gB1 + (size_t)64*K + k0, lB1 + 64*32);
        __syncthreads();

        short8 a[4];
        #pragma unroll
        for (int mt = 0; mt < 4; mt++) a[mt] = *(const short8*)(pa + mt*16*32);
        short8 b[4];
        #pragma unroll
        for (int nt = 0; nt < 4; nt++) b[nt] = *(const short8*)(pb1 + nt*16*32);
        #pragma unroll
        for (int mt = 0; mt < 4; mt++)
            #pragma unroll
            for (int nt = 0; nt < 4; nt++)
                acc1[mt][nt] = __builtin_amdgcn_mfma_f32_16x16x32_bf16(
                    a[mt], b[nt], acc1[mt][nt], 0, 0, 0);
        __syncthreads();
    }

    int ecol0 = n0 + wn + (lane & 15);
    int erow0 = m0 + wm + (lane >> 4) * 4;
    #pragma unroll
    for (int mt = 0; mt < 4; mt++) {
        int rowb = erow0 + mt * 16;
        int tok[4]; float wv[4];
        #pragma unroll
        for (int r = 0; r < 4; r++) {
            int row = rowb + r;
            tok[r] = (row < cnt) ? idxl[row] : -1;
            wv[r]  = (row < cnt) ? wgtl[row] : 0.f;
        }
        #pragma unroll
        for (int nt = 0; nt < 4; nt++) {
            int col = ecol0 + nt * 16;
            #pragma unroll
            for (int r = 0; r < 4; r++) {
                if (tok[r] >= 0)
                    atomicAdd(&out[(size_t)tok[r] * N + col],
                              wv[r] * (acc1[mt][nt][r] + bias1[col]));
            }
        }
    }
}

// ---------------- MFMA flash attention (bf16 in/out, f32 accum) -----------
__global__ __launch_bounds__(256)
void fattn_kernel(const ushort_t* __restrict__ q, const ushort_t* __restrict__ k,
                  const ushort_t* __restrict__ v, ushort_t* __restrict__ ctx)
{
    __shared__ __align__(16) ushort_t Ks[64*72];     // [k][d] padded
    __shared__ __align__(16) ushort_t Vt[64*72];     // [d][k] padded
    __shared__ __align__(16) ushort_t Ps[4][16*72];  // per-wave P [q][k]

    const int bid = blockIdx.x;
    const int qt = bid & (S_/64 - 1);
    const int h  = (bid >> 4) & (H_ - 1);
    const int b  = bid >> 8;
    const int tid = threadIdx.x;
    const int wave = tid >> 6, lane = tid & 63;
    const int RS = H_ * DK_;
    const size_t headbase = ((size_t)b * S_ * H_ + h) * DK_;
    const int s0 = qt * 64;
    const int lr = lane & 15, lg = lane >> 4;

    short8 qf0, qf1;
    {
        const ushort_t* qp = q + headbase + (size_t)(s0 + wave*16 + lr) * RS + lg * 8;
        qf0 = *(const short8*)qp;
        qf1 = *(const short8*)(qp + 32);
    }

    floatx4 O[4];
    float m_i[4], l_i[4];
    #pragma unroll
    for (int i = 0; i < 4; i++) { O[i] = (floatx4)(0.f); m_i[i] = -1e30f; l_i[i] = 0.f; }

    const int kr = tid >> 3, kc = (tid & 7) * 8;
    ushort_t* pw = Ps[wave];

    for (int t = 0; t < S_/64; t++) {
        const int kbase = t * 64;
        __syncthreads();
        {
            const ushort_t* kp = k + headbase + (size_t)(kbase + kr) * RS + kc;
            short8 k0 = *(const short8*)kp;
            short8 k1 = *(const short8*)(kp + (size_t)32 * RS);
            *(short8*)&Ks[kr*72 + kc]        = k0;
            *(short8*)&Ks[(kr + 32)*72 + kc] = k1;
        }
        {
            const ushort_t* vp = v + headbase + (size_t)(kbase + wave*16) * RS + lane;
            short8 w0, w1;
            #pragma unroll
            for (int j = 0; j < 8; j++) {
                ((ushort_t*)&w0)[j] = vp[(size_t)j * RS];
                ((ushort_t*)&w1)[j] = vp[(size_t)(j + 8) * RS];
            }
            *(short8*)&Vt[lane*72 + wave*16]     = w0;
            *(short8*)&Vt[lane*72 + wave*16 + 8] = w1;
        }
        __syncthreads();

        floatx4 sacc[4];
        #pragma unroll
        for (int nt = 0; nt < 4; nt++) sacc[nt] = (floatx4)(0.f);
        #pragma unroll
        for (int nt = 0; nt < 4; nt++) {
            short8 b0 = *(const short8*)&Ks[(lr + nt*16)*72 + lg*8];
            sacc[nt] = __builtin_amdgcn_mfma_f32_16x16x32_bf16(qf0, b0, sacc[nt], 0, 0, 0);
            short8 b1 = *(const short8*)&Ks[(lr + nt*16)*72 + 32 + lg*8];
            sacc[nt] = __builtin_amdgcn_mfma_f32_16x16x32_bf16(qf1, b1, sacc[nt], 0, 0, 0);
        }

        float alpha[4];
        #pragma unroll
        for (int r = 0; r < 4; r++) {
            float rm = -1e30f;
            #pragma unroll
            for (int nt = 0; nt < 4; nt++) { sacc[nt][r] *= 0.125f; rm = fmaxf(rm, sacc[nt][r]); }
            #pragma unroll
            for (int o = 1; o < 16; o <<= 1) rm = fmaxf(rm, __shfl_xor(rm, o, 64));
            float nm = fmaxf(m_i[r], rm);
            alpha[r] = __expf(m_i[r] - nm);
            m_i[r] = nm;
            float rs = 0.f;
            #pragma unroll
            for (int nt = 0; nt < 4; nt++) { sacc[nt][r] = __expf(sacc[nt][r] - nm); rs += sacc[nt][r]; }
            #pragma unroll
            for (int o = 1; o < 16; o <<= 1) rs += __shfl_xor(rs, o, 64);
            l_i[r] = l_i[r] * alpha[r] + rs;
        }

        #pragma unroll
        for (int nt = 0; nt < 4; nt++)
            #pragma unroll
            for (int r = 0; r < 4; r++)
                pw[(lg*4 + r)*72 + lr + nt*16] = f2bf(sacc[nt][r]);

        #pragma unroll
        for (int nt = 0; nt < 4; nt++)
            #pragma unroll
            for (int r = 0; r < 4; r++)
                O[nt][r] *= alpha[r];

        asm volatile("s_waitcnt lgkmcnt(0)" ::: "memory");

        #pragma unroll
        for (int kh = 0; kh < 2; kh++) {
            short8 pa = *(const short8*)&pw[lr*72 + kh*32 + lg*8];
            #pragma unroll
            for (int nt = 0; nt < 4; nt++) {
                short8 bv = *(const short8*)&Vt[(lr + nt*16)*72 + kh*32 + lg*8];
                O[nt] = __builtin_amdgcn_mfma_f32_16x16x32_bf16(pa, bv, O[nt], 0, 0, 0);
            }
        }
    }

    #pragma unroll
    for (int r = 0; r < 4; r++) {
        float inv = 1.f / l_i[r];
        #pragma unroll
        for (int nt = 0; nt < 4; nt++)
            pw[(lg*4 + r)*72 + lr + nt*16] = f2bf(O[nt][r] * inv);
    }
    asm volatile("s_waitcnt lgkmcnt(0)" ::: "memory");
    {
        const int row = lane >> 2, c0 = (lane & 3) * 16;
        short8 o0 = *(const short8*)&pw[row*72 + c0];
        short8 o1 = *(const short8*)&pw[row*72 + c0 + 8];
        ushort_t* gp = ctx + headbase + (size_t)(s0 + wave*16 + row) * RS + c0;
        *(short8*)gp       = o0;
        *(short8*)(gp + 8) = o1;
    }
}

extern "C" void kernel_launch(void* const* d_in, const int* in_sizes, int n_in,
                              void* d_out, int out_size, void* d_ws, size_t ws_size,
                              hipStream_t stream)
{
    const float* x    = (const float*)d_in[0];
    const float* wq1  = (const float*)d_in[2];
    const float* bq1  = (const float*)d_in[3];
    const float* wq2  = (const float*)d_in[4];
    const float* bq2  = (const float*)d_in[5];
    const float* wk1  = (const float*)d_in[6];
    const float* bk1  = (const float*)d_in[7];
    const float* wk2  = (const float*)d_in[8];
    const float* bk2  = (const float*)d_in[9];
    const float* wv1  = (const float*)d_in[10];
    const float* bv1  = (const float*)d_in[11];
    const float* wv2  = (const float*)d_in[12];
    const float* bv2  = (const float*)d_in[13];
    const float* wo   = (const float*)d_in[14];
    const float* bo   = (const float*)d_in[15];
    const float* ln1g = (const float*)d_in[16];
    const float* ln1b = (const float*)d_in[17];
    const float* ln2g = (const float*)d_in[18];
    const float* ln2b = (const float*)d_in[19];
    const float* gw   = (const float*)d_in[20];
    const float* gb   = (const float*)d_in[21];
    const float* ew1  = (const float*)d_in[22];
    const float* eb1  = (const float*)d_in[23];
    const float* ew2  = (const float*)d_in[24];
    const float* eb2  = (const float*)d_in[25];
    const float* ew3  = (const float*)d_in[26];
    const float* eb3  = (const float*)d_in[27];
    float* out = (float*)d_out;

    const size_t MB = 1024ull * 1024ull;
    char* w = (char*)d_ws;
    // ---- phase-1 arena [0, 54 MB): attention weights + activations ----
    ushort_t* wq1t = (ushort_t*)(w +  0*MB);
    ushort_t* wq2t = (ushort_t*)(w +  2*MB);
    ushort_t* wk1t = (ushort_t*)(w +  4*MB);
    ushort_t* wk2t = (ushort_t*)(w +  6*MB);
    ushort_t* wv1t = (ushort_t*)(w +  8*MB);
    ushort_t* wv2t = (ushort_t*)(w + 10*MB);
    ushort_t* wot  = (ushort_t*)(w + 12*MB);
    ushort_t* x2h  = (ushort_t*)(w + 14*MB);
    ushort_t* qh   = (ushort_t*)(w + 22*MB);
    ushort_t* kh   = (ushort_t*)(w + 30*MB);
    ushort_t* vh   = (ushort_t*)(w + 38*MB);
    ushort_t* ctxh = (ushort_t*)(w + 46*MB);
    // ---- phase-2 overlays (written only after phase-1 consumers done) ----
    ushort_t* e1t  = (ushort_t*)(w +  0*MB);   // [E][F][D] bf16, 32 MB (up)
    ushort_t* e3t  = (ushort_t*)(w + 32*MB);   // [E][F][D] bf16, 32 MB (up)
    ushort_t* e2t  = (ushort_t*)(w +  0*MB);   // [E][D][F] bf16, 32 MB (down; reuses e1t)
    // ---- persistent MoE state [64 MB, ~105.3 MB) ----
    ushort_t* x2bh = (ushort_t*)(w + 64*MB);   // 8 MB
    ushort_t* hAh  = (ushort_t*)(w + 72*MB);   // flat-compact [2*NTOK+128][F], ~32.5 MB
    char* tail = w + 105*MB;
    int*    cnts = (int*)tail;     tail += 256;
    int*    offs = (int*)tail;     tail += 256;
    int*    idxl = (int*)tail;     tail += (size_t)E_ * NTOK * 4;
    float*  wgtl = (float*)tail;   tail += (size_t)E_ * NTOK * 4;
    int*    tope = (int*)tail;     tail += (size_t)NTOK * 4;
    float2* topw = (float2*)tail;  tail += (size_t)NTOK * 8;

    dim3 blk(256);

    W7 p7;
    p7.s[0]=wq1; p7.d[0]=wq1t; p7.s[1]=wq2; p7.d[1]=wq2t;
    p7.s[2]=wk1; p7.d[2]=wk1t; p7.s[3]=wk2; p7.d[3]=wk2t;
    p7.s[4]=wv1; p7.d[4]=wv1t; p7.s[5]=wv2; p7.d[5]=wv2t;
    p7.s[6]=wo;  p7.d[6]=wot;
    transpose7<<<dim3(32,32,7), blk, 0, stream>>>(p7, D_, D_);

    // --- pre-norm attention ---
    ln_kernel<<<NTOK, blk, 0, stream>>>(x, ln1g, ln1b, x2h);
    QKV qp;
    qp.B1[0]=wq1t; qp.B2[0]=wq2t; qp.bias1[0]=bq1; qp.bias2[0]=bq2; qp.C[0]=qh;
    qp.B1[1]=wk1t; qp.B2[1]=wk2t; qp.bias1[1]=bk1; qp.bias2[1]=bk2; qp.C[1]=kh;
    qp.B1[2]=wv1t; qp.B2[2]=wv2t; qp.bias1[2]=bv1; qp.bias2[2]=bv2; qp.C[2]=vh;
    mgemm_qkv<<<dim3(D_/128, NTOK/128, 3), blk, 0, stream>>>(x2h, qp);
    fattn_kernel<<<B_ * H_ * (S_/64), blk, 0, stream>>>(qh, kh, vh, ctxh);
    mgemm_res<<<dim3(D_/128, NTOK/128), blk, 0, stream>>>(ctxh, wot, bo, x, out,
                                                          NTOK, D_, D_);

    // --- pre-norm MoE SwiGLU FFN (top-2 sparse), gate fused into LN ---
    ln_gate_kernel<<<NTOK, blk, 0, stream>>>(out, ln2g, ln2b, x2bh, gw, gb,
                                             tope, topw);
    build_lists<<<dim3(E_), blk, 0, stream>>>(tope, topw, cnts, offs, idxl, wgtl);
    // phase-1 buffers are dead from here; overlay expert weights.
    transpose_e13<<<dim3(F_/32, D_/32, 2*E_), blk, 0, stream>>>(ew1, ew3, e1t, e3t);
    mgemm_up_all<<<dim3(F_/128, NTOK/128, E_), blk, 0, stream>>>(
        x2bh, idxl, cnts, offs, e1t, eb1, e3t, eb3, hAh);
    transpose_e2<<<dim3(D_/32, F_/32, E_), blk, 0, stream>>>(ew2, e2t);
    mgemm_down_all<<<dim3(D_/128, NTOK/128, E_), blk, 0, stream>>>(
        hAh, idxl, wgtl, cnts, offs, e2t, eb2, out);
}

// Round 6
// 745.135 us; speedup vs baseline: 2.3931x; 1.1640x over previous
//
#include <hip/hip_runtime.h>
#include <math.h>

#define B_ 4
#define S_ 1024
#define D_ 1024
#define F_ 2048
#define H_ 16
#define E_ 8
#define DK_ 64
#define NTOK (B_*S_)

typedef unsigned short ushort_t;
typedef __attribute__((ext_vector_type(8))) short short8;
typedef __attribute__((ext_vector_type(4))) float floatx4;

// ---- bf16 helpers (RNE) ----
__device__ __forceinline__ ushort_t f2bf(float f) {
    unsigned u = __float_as_uint(f);
    unsigned r = (u + 0x7fffu + ((u >> 16) & 1u)) >> 16;
    return (ushort_t)r;
}
__device__ __forceinline__ float bf2f(ushort_t h) {
    return __uint_as_float(((unsigned)h) << 16);
}

// ---- async global->LDS 16B ----
__device__ __forceinline__ void gload16(const void* g, void* l) {
    __builtin_amdgcn_global_load_lds(
        (const __attribute__((address_space(1))) unsigned*)g,
        (__attribute__((address_space(3))) unsigned*)l, 16, 0, 0);
}

// ---------------- block reductions (256 threads = 4 waves) ----------------
__device__ __forceinline__ float blockReduceSum256(float v, volatile float* sred) {
    int tid = threadIdx.x;
    #pragma unroll
    for (int o = 32; o > 0; o >>= 1) v += __shfl_down(v, o, 64);
    __syncthreads();
    if ((tid & 63) == 0) sred[tid >> 6] = v;
    __syncthreads();
    return sred[0] + sred[1] + sred[2] + sred[3];
}

// ---------------- LayerNorm: one block per row; writes bf16 ---------------
__global__ __launch_bounds__(256)
void ln_kernel(const float* __restrict__ x, const float* __restrict__ g,
               const float* __restrict__ b, ushort_t* __restrict__ yh) {
    __shared__ float sred[4];
    int row = blockIdx.x;
    int tid = threadIdx.x;
    const float* xr = x + (size_t)row * D_;
    float v[4];
    float s = 0.f;
    #pragma unroll
    for (int i = 0; i < 4; i++) { v[i] = xr[tid + 256*i]; s += v[i]; }
    float mean = blockReduceSum256(s, sred) * (1.f / D_);
    float s2 = 0.f;
    #pragma unroll
    for (int i = 0; i < 4; i++) { float d = v[i] - mean; s2 += d * d; }
    float var = blockReduceSum256(s2, sred) * (1.f / D_);
    float rstd = rsqrtf(var + 1e-5f);
    #pragma unroll
    for (int i = 0; i < 4; i++) {
        int c = tid + 256*i;
        float r = (v[i] - mean) * rstd * g[c] + b[c];
        yh[(size_t)row * D_ + c] = f2bf(r);
    }
}

// ------- LayerNorm fused with MoE gate (softmax + top-2, NO atomics) ------
__global__ __launch_bounds__(256)
void ln_gate_kernel(const float* __restrict__ x, const float* __restrict__ g,
                    const float* __restrict__ b, ushort_t* __restrict__ yh,
                    const float* __restrict__ gw, const float* __restrict__ gb,
                    int* __restrict__ tope, float2* __restrict__ topw) {
    __shared__ float sred[4];
    __shared__ float sgate[4][E_];
    int row = blockIdx.x;
    int tid = threadIdx.x;
    const float* xr = x + (size_t)row * D_;
    float v[4];
    float s = 0.f;
    #pragma unroll
    for (int i = 0; i < 4; i++) { v[i] = xr[tid + 256*i]; s += v[i]; }
    float mean = blockReduceSum256(s, sred) * (1.f / D_);
    float s2 = 0.f;
    #pragma unroll
    for (int i = 0; i < 4; i++) { float d = v[i] - mean; s2 += d * d; }
    float var = blockReduceSum256(s2, sred) * (1.f / D_);
    float rstd = rsqrtf(var + 1e-5f);

    float p[E_];
    #pragma unroll
    for (int e = 0; e < E_; e++) p[e] = 0.f;
    #pragma unroll
    for (int i = 0; i < 4; i++) {
        int c = tid + 256*i;
        float r = (v[i] - mean) * rstd * g[c] + b[c];
        yh[(size_t)row * D_ + c] = f2bf(r);
        const float* gwr = gw + (size_t)c * E_;
        #pragma unroll
        for (int e = 0; e < E_; e++) p[e] += r * gwr[e];
    }
    #pragma unroll
    for (int o = 32; o > 0; o >>= 1)
        #pragma unroll
        for (int e = 0; e < E_; e++) p[e] += __shfl_down(p[e], o, 64);
    __syncthreads();
    if ((tid & 63) == 0) {
        #pragma unroll
        for (int e = 0; e < E_; e++) sgate[tid >> 6][e] = p[e];
    }
    __syncthreads();
    if (tid == 0) {
        float q[E_];
        float mx = -1e30f;
        #pragma unroll
        for (int e = 0; e < E_; e++) {
            q[e] = sgate[0][e] + sgate[1][e] + sgate[2][e] + sgate[3][e] + gb[e];
            mx = fmaxf(mx, q[e]);
        }
        float sum = 0.f;
        #pragma unroll
        for (int e = 0; e < E_; e++) { q[e] = expf(q[e] - mx); sum += q[e]; }
        #pragma unroll
        for (int e = 0; e < E_; e++) q[e] /= sum;
        int i1 = 0;
        #pragma unroll
        for (int e = 1; e < E_; e++) if (q[e] > q[i1]) i1 = e;
        int i2 = (i1 == 0) ? 1 : 0;
        #pragma unroll
        for (int e = 0; e < E_; e++) if (e != i2 && e != i1 && q[e] > q[i2]) i2 = e;
        float denom = q[i1] + q[i2] + 1e-6f;
        tope[row] = i1 | (i2 << 8);
        topw[row] = make_float2(q[i1] / denom, q[i2] / denom);
    }
}

// ------- build per-expert token lists + flat offsets (no atomics) ---------
__global__ __launch_bounds__(256)
void build_lists(const int* __restrict__ tope, const float2* __restrict__ topw,
                 int* __restrict__ counts, int* __restrict__ offs,
                 int* __restrict__ idxl, float* __restrict__ wgtl)
{
    const int e = blockIdx.x;
    const int tid = threadIdx.x;
    const int lane = tid & 63, wv = tid >> 6;
    __shared__ int wsum[4];
    __shared__ int sbase;
    __shared__ int ctot[4][E_];
    if (tid == 0) sbase = 0;
    __syncthreads();
    int* il = idxl + (size_t)e * NTOK;
    float* wl = wgtl + (size_t)e * NTOK;
    int c8[E_];
    #pragma unroll
    for (int i = 0; i < E_; i++) c8[i] = 0;
    for (int t0 = 0; t0 < NTOK; t0 += 256) {
        int t = t0 + tid;
        int pk = tope[t];
        int i1 = pk & 255, i2 = (pk >> 8) & 255;
        #pragma unroll
        for (int i = 0; i < E_; i++) c8[i] += (i1 == i) + (i2 == i);
        bool m = (i1 == e) || (i2 == e);
        float2 wp = topw[t];
        float w = (i1 == e) ? wp.x : wp.y;
        unsigned long long mask = __ballot(m);
        int wpos = __popcll(mask & ((1ull << lane) - 1ull));
        int wcnt = __popcll(mask);
        if (lane == 0) wsum[wv] = wcnt;
        __syncthreads();
        int base = sbase;
        int pre = 0;
        #pragma unroll
        for (int i = 0; i < 4; i++) if (i < wv) pre += wsum[i];
        if (m) { il[base + pre + wpos] = t; wl[base + pre + wpos] = w; }
        __syncthreads();
        if (tid == 0) sbase = base + wsum[0] + wsum[1] + wsum[2] + wsum[3];
    }
    #pragma unroll
    for (int i = 0; i < E_; i++)
        #pragma unroll
        for (int o = 32; o > 0; o >>= 1) c8[i] += __shfl_down(c8[i], o, 64);
    if (lane == 0) {
        #pragma unroll
        for (int i = 0; i < E_; i++) ctot[wv][i] = c8[i];
    }
    __syncthreads();
    if (tid == 0) {
        int off = 0;
        for (int i = 0; i < e; i++)
            off += ctot[0][i] + ctot[1][i] + ctot[2][i] + ctot[3][i];
        offs[e] = off;
        counts[e] = sbase;
    }
}

// ------- attention weight transposes: 7 matrices, one dispatch ------------
struct W7 { const float* s[7]; ushort_t* d[7]; };
__global__ __launch_bounds__(256)
void transpose7(W7 p, int R, int C)
{
    const float* s = p.s[blockIdx.z];
    ushort_t* d = p.d[blockIdx.z];
    __shared__ float t[32][33];
    int r0 = blockIdx.y * 32, c0 = blockIdx.x * 32;
    int lr = threadIdx.x >> 3, lc = (threadIdx.x & 7) * 4;
    float4 v = *(const float4*)(s + (size_t)(r0 + lr) * C + c0 + lc);
    t[lr][lc+0] = v.x; t[lr][lc+1] = v.y; t[lr][lc+2] = v.z; t[lr][lc+3] = v.w;
    __syncthreads();
    ushort4 o;
    o.x = f2bf(t[lc+0][lr]); o.y = f2bf(t[lc+1][lr]);
    o.z = f2bf(t[lc+2][lr]); o.w = f2bf(t[lc+3][lr]);
    *(ushort4*)(d + (size_t)(c0 + lr) * R + r0 + lc) = o;
}

// ------- expert up-proj weight transposes (ew1 & ew3), one dispatch -------
__global__ __launch_bounds__(256)
void transpose_e13(const float* __restrict__ ew1, const float* __restrict__ ew3,
                   ushort_t* __restrict__ e1t, ushort_t* __restrict__ e3t)
{
    const int z = blockIdx.z;
    const int e = z >> 1, which = z & 1;
    const float* s = (which ? ew3 : ew1) + (size_t)e * D_ * F_;
    ushort_t* d = (which ? e3t : e1t) + (size_t)e * D_ * F_;
    const int R = D_, C = F_;
    int r0 = blockIdx.y * 32, c0 = blockIdx.x * 32;
    __shared__ float t[32][33];
    int lr = threadIdx.x >> 3, lc = (threadIdx.x & 7) * 4;
    float4 v = *(const float4*)(s + (size_t)(r0 + lr) * C + c0 + lc);
    t[lr][lc+0] = v.x; t[lr][lc+1] = v.y; t[lr][lc+2] = v.z; t[lr][lc+3] = v.w;
    __syncthreads();
    ushort4 o;
    o.x = f2bf(t[lc+0][lr]); o.y = f2bf(t[lc+1][lr]);
    o.z = f2bf(t[lc+2][lr]); o.w = f2bf(t[lc+3][lr]);
    *(ushort4*)(d + (size_t)(c0 + lr) * R + r0 + lc) = o;
}

// ------- expert down-proj weight transpose (ew2), one dispatch ------------
__global__ __launch_bounds__(256)
void transpose_e2(const float* __restrict__ ew2, ushort_t* __restrict__ e2t)
{
    const int e = blockIdx.z;
    const float* s = ew2 + (size_t)e * F_ * D_;
    ushort_t* d = e2t + (size_t)e * F_ * D_;
    const int R = F_, C = D_;
    int r0 = blockIdx.y * 32, c0 = blockIdx.x * 32;
    __shared__ float t[32][33];
    int lr = threadIdx.x >> 3, lc = (threadIdx.x & 7) * 4;
    float4 v = *(const float4*)(s + (size_t)(r0 + lr) * C + c0 + lc);
    t[lr][lc+0] = v.x; t[lr][lc+1] = v.y; t[lr][lc+2] = v.z; t[lr][lc+3] = v.w;
    __syncthreads();
    ushort4 o;
    o.x = f2bf(t[lc+0][lr]); o.y = f2bf(t[lc+1][lr]);
    o.z = f2bf(t[lc+2][lr]); o.w = f2bf(t[lc+3][lr]);
    *(ushort4*)(d + (size_t)(c0 + lr) * R + r0 + lc) = o;
}

// ---------------- MFMA bf16 GEMM (2-phase dbuf): C = A @ B^T + bias + R ---
// 128x128 tile, BK=32, 256 thr, double-buffered LDS; loads for tile k+1
// are issued before compute of tile k; __syncthreads' implicit vmcnt(0)
// drain lands AFTER compute covers the latency.
__global__ __launch_bounds__(256)
void mgemm_res(const ushort_t* __restrict__ A, const ushort_t* __restrict__ B1,
               const float* __restrict__ bias1, const float* __restrict__ R,
               float* __restrict__ Cv, int M, int N, int K)
{
    __shared__ __align__(16) ushort_t As [2][128*32];
    __shared__ __align__(16) ushort_t Bs1[2][128*32];

    int tid = threadIdx.x;
    int m0 = blockIdx.y * 128, n0 = blockIdx.x * 128;
    int trow = tid >> 2;
    int tcol = (tid & 3) * 8;
    const ushort_t* gA  = A  + (size_t)(m0 + trow) * K + tcol;
    const ushort_t* gB1 = B1 + (size_t)(n0 + trow) * K + tcol;
    const int lofs = trow*32 + tcol;

    int wave = tid >> 6, lane = tid & 63;
    int wm = (wave >> 1) * 64, wn = (wave & 1) * 64;
    int fr = lane & 15, fk = (lane >> 4) * 8;
    const int pofsA = (wm + fr)*32 + fk;
    const int pofsB = (wn + fr)*32 + fk;

    floatx4 acc1[4][4];
    #pragma unroll
    for (int i = 0; i < 4; i++)
        #pragma unroll
        for (int j = 0; j < 4; j++) acc1[i][j] = (floatx4)(0.f);

    // prologue: stage tile 0 into buffer 0
    gload16(gA,                  &As [0][lofs]);
    gload16(gA  + (size_t)64*K,  &As [0][lofs + 64*32]);
    gload16(gB1,                 &Bs1[0][lofs]);
    gload16(gB1 + (size_t)64*K,  &Bs1[0][lofs + 64*32]);
    __syncthreads();

    int cur = 0;
    for (int k0 = 0; k0 < K; k0 += 32) {
        int nxt = cur ^ 1;
        if (k0 + 32 < K) {
            gload16(gA  + k0 + 32,                 &As [nxt][lofs]);
            gload16(gA  + (size_t)64*K + k0 + 32,  &As [nxt][lofs + 64*32]);
            gload16(gB1 + k0 + 32,                 &Bs1[nxt][lofs]);
            gload16(gB1 + (size_t)64*K + k0 + 32,  &Bs1[nxt][lofs + 64*32]);
        }
        short8 a[4];
        #pragma unroll
        for (int mt = 0; mt < 4; mt++) a[mt] = *(const short8*)&As[cur][pofsA + mt*16*32];
        short8 b[4];
        #pragma unroll
        for (int nt = 0; nt < 4; nt++) b[nt] = *(const short8*)&Bs1[cur][pofsB + nt*16*32];
        #pragma unroll
        for (int mt = 0; mt < 4; mt++)
            #pragma unroll
            for (int nt = 0; nt < 4; nt++)
                acc1[mt][nt] = __builtin_amdgcn_mfma_f32_16x16x32_bf16(
                    a[mt], b[nt], acc1[mt][nt], 0, 0, 0);
        __syncthreads();
        cur = nxt;
    }

    int ecol0 = n0 + wn + (lane & 15);
    int erow0 = m0 + wm + (lane >> 4) * 4;
    #pragma unroll
    for (int mt = 0; mt < 4; mt++) {
        #pragma unroll
        for (int nt = 0; nt < 4; nt++) {
            int col = ecol0 + nt * 16;
            #pragma unroll
            for (int r = 0; r < 4; r++) {
                int row = erow0 + mt * 16 + r;
                size_t idx = (size_t)row * N + col;
                Cv[idx] = acc1[mt][nt][r] + bias1[col] + R[idx];
            }
        }
    }
}

// ---------------- fused Q/K/V dual-B SwiGLU projections (2-phase dbuf) ----
struct QKV {
    const ushort_t* B1[3]; const ushort_t* B2[3];
    const float* bias1[3]; const float* bias2[3];
    ushort_t* C[3];
};
__global__ __launch_bounds__(256)
void mgemm_qkv(const ushort_t* __restrict__ A, QKV p)
{
    const int z = blockIdx.z;
    const ushort_t* B1 = p.B1[z];
    const ushort_t* B2 = p.B2[z];
    const float* bias1 = p.bias1[z];
    const float* bias2 = p.bias2[z];
    ushort_t* C = p.C[z];
    const int N = D_, K = D_;

    __shared__ __align__(16) ushort_t As [2][128*32];
    __shared__ __align__(16) ushort_t Bs1[2][128*32];
    __shared__ __align__(16) ushort_t Bs2[2][128*32];

    int tid = threadIdx.x;
    int m0 = blockIdx.y * 128, n0 = blockIdx.x * 128;
    int trow = tid >> 2;
    int tcol = (tid & 3) * 8;
    const ushort_t* gA  = A  + (size_t)(m0 + trow) * K + tcol;
    const ushort_t* gB1 = B1 + (size_t)(n0 + trow) * K + tcol;
    const ushort_t* gB2 = B2 + (size_t)(n0 + trow) * K + tcol;
    const int lofs = trow*32 + tcol;

    int wave = tid >> 6, lane = tid & 63;
    int wm = (wave >> 1) * 64, wn = (wave & 1) * 64;
    int fr = lane & 15, fk = (lane >> 4) * 8;
    const int pofsA = (wm + fr)*32 + fk;
    const int pofsB = (wn + fr)*32 + fk;

    floatx4 acc1[4][4], acc2[4][4];
    #pragma unroll
    for (int i = 0; i < 4; i++)
        #pragma unroll
        for (int j = 0; j < 4; j++) { acc1[i][j] = (floatx4)(0.f); acc2[i][j] = (floatx4)(0.f); }

    gload16(gA,                  &As [0][lofs]);
    gload16(gA  + (size_t)64*K,  &As [0][lofs + 64*32]);
    gload16(gB1,                 &Bs1[0][lofs]);
    gload16(gB1 + (size_t)64*K,  &Bs1[0][lofs + 64*32]);
    gload16(gB2,                 &Bs2[0][lofs]);
    gload16(gB2 + (size_t)64*K,  &Bs2[0][lofs + 64*32]);
    __syncthreads();

    int cur = 0;
    for (int k0 = 0; k0 < K; k0 += 32) {
        int nxt = cur ^ 1;
        if (k0 + 32 < K) {
            gload16(gA  + k0 + 32,                 &As [nxt][lofs]);
            gload16(gA  + (size_t)64*K + k0 + 32,  &As [nxt][lofs + 64*32]);
            gload16(gB1 + k0 + 32,                 &Bs1[nxt][lofs]);
            gload16(gB1 + (size_t)64*K + k0 + 32,  &Bs1[nxt][lofs + 64*32]);
            gload16(gB2 + k0 + 32,                 &Bs2[nxt][lofs]);
            gload16(gB2 + (size_t)64*K + k0 + 32,  &Bs2[nxt][lofs + 64*32]);
        }
        short8 a[4];
        #pragma unroll
        for (int mt = 0; mt < 4; mt++) a[mt] = *(const short8*)&As[cur][pofsA + mt*16*32];
        {
            short8 b[4];
            #pragma unroll
            for (int nt = 0; nt < 4; nt++) b[nt] = *(const short8*)&Bs1[cur][pofsB + nt*16*32];
            #pragma unroll
            for (int mt = 0; mt < 4; mt++)
                #pragma unroll
                for (int nt = 0; nt < 4; nt++)
                    acc1[mt][nt] = __builtin_amdgcn_mfma_f32_16x16x32_bf16(
                        a[mt], b[nt], acc1[mt][nt], 0, 0, 0);
        }
        {
            short8 b[4];
            #pragma unroll
            for (int nt = 0; nt < 4; nt++) b[nt] = *(const short8*)&Bs2[cur][pofsB + nt*16*32];
            #pragma unroll
            for (int mt = 0; mt < 4; mt++)
                #pragma unroll
                for (int nt = 0; nt < 4; nt++)
                    acc2[mt][nt] = __builtin_amdgcn_mfma_f32_16x16x32_bf16(
                        a[mt], b[nt], acc2[mt][nt], 0, 0, 0);
        }
        __syncthreads();
        cur = nxt;
    }

    int ecol0 = n0 + wn + (lane & 15);
    int erow0 = m0 + wm + (lane >> 4) * 4;
    #pragma unroll
    for (int mt = 0; mt < 4; mt++) {
        #pragma unroll
        for (int nt = 0; nt < 4; nt++) {
            int col = ecol0 + nt * 16;
            #pragma unroll
            for (int r = 0; r < 4; r++) {
                int row = erow0 + mt * 16 + r;
                float x1 = acc1[mt][nt][r] + bias1[col];
                float x2 = acc2[mt][nt][r] + bias2[col];
                float h = x1 / (1.f + __expf(-x1)) * x2;
                C[(size_t)row * N + col] = f2bf(h);
            }
        }
    }
}

// ------- fused MoE up-proj over all experts (2-phase dbuf, gathered A) ----
__global__ __launch_bounds__(256)
void mgemm_up_all(const ushort_t* __restrict__ A, const int* __restrict__ idxl_all,
                  const int* __restrict__ counts, const int* __restrict__ offs,
                  const ushort_t* __restrict__ B1a, const float* __restrict__ b1a,
                  const ushort_t* __restrict__ B2a, const float* __restrict__ b2a,
                  ushort_t* __restrict__ Call)
{
    const int e = blockIdx.z;
    int cnt = counts[e];
    int m0 = blockIdx.y * 128;
    if (m0 >= cnt) return;
    const int N = F_, K = D_;
    const int* idxl = idxl_all + (size_t)e * NTOK;
    const ushort_t* B1 = B1a + (size_t)e * D_ * F_;
    const ushort_t* B2 = B2a + (size_t)e * D_ * F_;
    const float* bias1 = b1a + (size_t)e * F_;
    const float* bias2 = b2a + (size_t)e * F_;
    ushort_t* C = Call + (size_t)offs[e] * F_;

    __shared__ __align__(16) ushort_t As [2][128*32];
    __shared__ __align__(16) ushort_t Bs1[2][128*32];
    __shared__ __align__(16) ushort_t Bs2[2][128*32];

    int tid = threadIdx.x;
    int n0 = blockIdx.x * 128;
    int trow = tid >> 2;
    int tcol = (tid & 3) * 8;
    int r0 = m0 + trow, r1 = m0 + 64 + trow;
    int t0 = (r0 < cnt) ? idxl[r0] : 0;
    int t1 = (r1 < cnt) ? idxl[r1] : 0;
    const ushort_t* gA0 = A + (size_t)t0 * K + tcol;
    const ushort_t* gA1 = A + (size_t)t1 * K + tcol;
    const ushort_t* gB1 = B1 + (size_t)(n0 + trow) * K + tcol;
    const ushort_t* gB2 = B2 + (size_t)(n0 + trow) * K + tcol;
    const int lofs = trow*32 + tcol;

    int wave = tid >> 6, lane = tid & 63;
    int wm = (wave >> 1) * 64, wn = (wave & 1) * 64;
    int fr = lane & 15, fk = (lane >> 4) * 8;
    const int pofsA = (wm + fr)*32 + fk;
    const int pofsB = (wn + fr)*32 + fk;

    floatx4 acc1[4][4], acc2[4][4];
    #pragma unroll
    for (int i = 0; i < 4; i++)
        #pragma unroll
        for (int j = 0; j < 4; j++) { acc1[i][j] = (floatx4)(0.f); acc2[i][j] = (floatx4)(0.f); }

    gload16(gA0,                 &As [0][lofs]);
    gload16(gA1,                 &As [0][lofs + 64*32]);
    gload16(gB1,                 &Bs1[0][lofs]);
    gload16(gB1 + (size_t)64*K,  &Bs1[0][lofs + 64*32]);
    gload16(gB2,                 &Bs2[0][lofs]);
    gload16(gB2 + (size_t)64*K,  &Bs2[0][lofs + 64*32]);
    __syncthreads();

    int cur = 0;
    for (int k0 = 0; k0 < K; k0 += 32) {
        int nxt = cur ^ 1;
        if (k0 + 32 < K) {
            gload16(gA0 + k0 + 32,                 &As [nxt][lofs]);
            gload16(gA1 + k0 + 32,                 &As [nxt][lofs + 64*32]);
            gload16(gB1 + k0 + 32,                 &Bs1[nxt][lofs]);
            gload16(gB1 + (size_t)64*K + k0 + 32,  &Bs1[nxt][lofs + 64*32]);
            gload16(gB2 + k0 + 32,                 &Bs2[nxt][lofs]);
            gload16(gB2 + (size_t)64*K + k0 + 32,  &Bs2[nxt][lofs + 64*32]);
        }
        short8 a[4];
        #pragma unroll
        for (int mt = 0; mt < 4; mt++) a[mt] = *(const short8*)&As[cur][pofsA + mt*16*32];
        {
            short8 b[4];
            #pragma unroll
            for (int nt = 0; nt < 4; nt++) b[nt] = *(const short8*)&Bs1[cur][pofsB + nt*16*32];
            #pragma unroll
            for (int mt = 0; mt < 4; mt++)
                #pragma unroll
                for (int nt = 0; nt < 4; nt++)
                    acc1[mt][nt] = __builtin_amdgcn_mfma_f32_16x16x32_bf16(
                        a[mt], b[nt], acc1[mt][nt], 0, 0, 0);
        }
        {
            short8 b[4];
            #pragma unroll
            for (int nt = 0; nt < 4; nt++) b[nt] = *(const short8*)&Bs2[cur][pofsB + nt*16*32];
            #pragma unroll
            for (int mt = 0; mt < 4; mt++)
                #pragma unroll
                for (int nt = 0; nt < 4; nt++)
                    acc2[mt][nt] = __builtin_amdgcn_mfma_f32_16x16x32_bf16(
                        a[mt], b[nt], acc2[mt][nt], 0, 0, 0);
        }
        __syncthreads();
        cur = nxt;
    }

    int ecol0 = n0 + wn + (lane & 15);
    int erow0 = m0 + wm + (lane >> 4) * 4;
    #pragma unroll
    for (int mt = 0; mt < 4; mt++) {
        #pragma unroll
        for (int nt = 0; nt < 4; nt++) {
            int col = ecol0 + nt * 16;
            #pragma unroll
            for (int r = 0; r < 4; r++) {
                int row = erow0 + mt * 16 + r;
                if (row < cnt) {
                    float x1 = acc1[mt][nt][r] + bias1[col];
                    float x2 = acc2[mt][nt][r] + bias2[col];
                    float h = x1 / (1.f + __expf(-x1)) * x2;
                    C[(size_t)row * N + col] = f2bf(h);
                }
            }
        }
    }
}

// ------- fused MoE down-proj over all experts (2-phase dbuf) --------------
__global__ __launch_bounds__(256)
void mgemm_down_all(const ushort_t* __restrict__ hA, const int* __restrict__ idxl_all,
                    const float* __restrict__ wgtl_all, const int* __restrict__ counts,
                    const int* __restrict__ offs, const ushort_t* __restrict__ B1a,
                    const float* __restrict__ b1a, float* __restrict__ out)
{
    const int e = blockIdx.z;
    int cnt = counts[e];
    int m0 = blockIdx.y * 128;
    if (m0 >= cnt) return;
    const int N = D_, K = F_;
    const int* idxl = idxl_all + (size_t)e * NTOK;
    const float* wgtl = wgtl_all + (size_t)e * NTOK;
    const ushort_t* A = hA + (size_t)offs[e] * F_;
    const ushort_t* B1 = B1a + (size_t)e * F_ * D_;
    const float* bias1 = b1a + (size_t)e * D_;

    __shared__ __align__(16) ushort_t As [2][128*32];
    __shared__ __align__(16) ushort_t Bs1[2][128*32];

    int tid = threadIdx.x;
    int n0 = blockIdx.x * 128;
    int trow = tid >> 2;
    int tcol = (tid & 3) * 8;
    const ushort_t* gA  = A  + (size_t)(m0 + trow) * K + tcol;
    const ushort_t* gB1 = B1 + (size_t)(n0 + trow) * K + tcol;
    const int lofs = trow*32 + tcol;

    int wave = tid >> 6, lane = tid & 63;
    int wm = (wave >> 1) * 64, wn = (wave & 1) * 64;
    int fr = lane & 15, fk = (lane >> 4) * 8;
    const int pofsA = (wm + fr)*32 + fk;
    const int pofsB = (wn + fr)*32 + fk;

    floatx4 acc1[4][4];
    #pragma unroll
    for (int i = 0; i < 4; i++)
        #pragma unroll
        for (int j = 0; j < 4; j++) acc1[i][j] = (floatx4)(0.f);

    gload16(gA,                  &As [0][lofs]);
    gload16(gA  + (size_t)64*K,  &As [0][lofs + 64*32]);
    gload16(gB1,                 &Bs1[0][lofs]);
    gload16(gB1 + (size_t)64*K,  &Bs1[0][lofs + 64*32]);
    __syncthreads();

    int cur = 0;
    for (int k0 = 0; k0 < K; k0 += 32) {
        int nxt = cur ^ 1;
        if (k0 + 32 < K) {
            gload16(gA  + k0 + 32,                 &As [nxt][lofs]);
            gload16(gA  + (size_t)64*K + k0 + 32,  &As [nxt][lofs + 64*32]);
            gload16(gB1 + k0 + 32,                 &Bs1[nxt][lofs]);
            gload16(gB1 + (size_t)64*K + k0 + 32,  &Bs1[nxt][lofs + 64*32]);
        }
        short8 a[4];
        #pragma unroll
        for (int mt = 0; mt < 4; mt++) a[mt] = *(const short8*)&As[cur][pofsA + mt*16*32];
        short8 b[4];
        #pragma unroll
        for (int nt = 0; nt < 4; nt++) b[nt] = *(const short8*)&Bs1[cur][pofsB + nt*16*32];
        #pragma unroll
        for (int mt = 0; mt < 4; mt++)
            #pragma unroll
            for (int nt = 0; nt < 4; nt++)
                acc1[mt][nt] = __builtin_amdgcn_mfma_f32_16x16x32_bf16(
                    a[mt], b[nt], acc1[mt][nt], 0, 0, 0);
        __syncthreads();
        cur = nxt;
    }

    int ecol0 = n0 + wn + (lane & 15);
    int erow0 = m0 + wm + (lane >> 4) * 4;
    #pragma unroll
    for (int mt = 0; mt < 4; mt++) {
        int rowb = erow0 + mt * 16;
        int tok[4]; float wv[4];
        #pragma unroll
        for (int r = 0; r < 4; r++) {
            int row = rowb + r;
            tok[r] = (row < cnt) ? idxl[row] : -1;
            wv[r]  = (row < cnt) ? wgtl[row] : 0.f;
        }
        #pragma unroll
        for (int nt = 0; nt < 4; nt++) {
            int col = ecol0 + nt * 16;
            #pragma unroll
            for (int r = 0; r < 4; r++) {
                if (tok[r] >= 0)
                    atomicAdd(&out[(size_t)tok[r] * N + col],
                              wv[r] * (acc1[mt][nt][r] + bias1[col]));
            }
        }
    }
}

// ---------------- MFMA flash attention (bf16 in/out, f32 accum) -----------
__global__ __launch_bounds__(256)
void fattn_kernel(const ushort_t* __restrict__ q, const ushort_t* __restrict__ k,
                  const ushort_t* __restrict__ v, ushort_t* __restrict__ ctx)
{
    __shared__ __align__(16) ushort_t Ks[64*72];     // [k][d] padded
    __shared__ __align__(16) ushort_t Vt[64*72];     // [d][k] padded
    __shared__ __align__(16) ushort_t Ps[4][16*72];  // per-wave P [q][k]

    const int bid = blockIdx.x;
    const int qt = bid & (S_/64 - 1);
    const int h  = (bid >> 4) & (H_ - 1);
    const int b  = bid >> 8;
    const int tid = threadIdx.x;
    const int wave = tid >> 6, lane = tid & 63;
    const int RS = H_ * DK_;
    const size_t headbase = ((size_t)b * S_ * H_ + h) * DK_;
    const int s0 = qt * 64;
    const int lr = lane & 15, lg = lane >> 4;

    short8 qf0, qf1;
    {
        const ushort_t* qp = q + headbase + (size_t)(s0 + wave*16 + lr) * RS + lg * 8;
        qf0 = *(const short8*)qp;
        qf1 = *(const short8*)(qp + 32);
    }

    floatx4 O[4];
    float m_i[4], l_i[4];
    #pragma unroll
    for (int i = 0; i < 4; i++) { O[i] = (floatx4)(0.f); m_i[i] = -1e30f; l_i[i] = 0.f; }

    const int kr = tid >> 3, kc = (tid & 7) * 8;
    ushort_t* pw = Ps[wave];

    for (int t = 0; t < S_/64; t++) {
        const int kbase = t * 64;
        __syncthreads();
        {
            const ushort_t* kp = k + headbase + (size_t)(kbase + kr) * RS + kc;
            short8 k0 = *(const short8*)kp;
            short8 k1 = *(const short8*)(kp + (size_t)32 * RS);
            *(short8*)&Ks[kr*72 + kc]        = k0;
            *(short8*)&Ks[(kr + 32)*72 + kc] = k1;
        }
        {
            const ushort_t* vp = v + headbase + (size_t)(kbase + wave*16) * RS + lane;
            short8 w0, w1;
            #pragma unroll
            for (int j = 0; j < 8; j++) {
                ((ushort_t*)&w0)[j] = vp[(size_t)j * RS];
                ((ushort_t*)&w1)[j] = vp[(size_t)(j + 8) * RS];
            }
            *(short8*)&Vt[lane*72 + wave*16]     = w0;
            *(short8*)&Vt[lane*72 + wave*16 + 8] = w1;
        }
        __syncthreads();

        floatx4 sacc[4];
        #pragma unroll
        for (int nt = 0; nt < 4; nt++) sacc[nt] = (floatx4)(0.f);
        #pragma unroll
        for (int nt = 0; nt < 4; nt++) {
            short8 b0 = *(const short8*)&Ks[(lr + nt*16)*72 + lg*8];
            sacc[nt] = __builtin_amdgcn_mfma_f32_16x16x32_bf16(qf0, b0, sacc[nt], 0, 0, 0);
            short8 b1 = *(const short8*)&Ks[(lr + nt*16)*72 + 32 + lg*8];
            sacc[nt] = __builtin_amdgcn_mfma_f32_16x16x32_bf16(qf1, b1, sacc[nt], 0, 0, 0);
        }

        float alpha[4];
        #pragma unroll
        for (int r = 0; r < 4; r++) {
            float rm = -1e30f;
            #pragma unroll
            for (int nt = 0; nt < 4; nt++) { sacc[nt][r] *= 0.125f; rm = fmaxf(rm, sacc[nt][r]); }
            #pragma unroll
            for (int o = 1; o < 16; o <<= 1) rm = fmaxf(rm, __shfl_xor(rm, o, 64));
            float nm = fmaxf(m_i[r], rm);
            alpha[r] = __expf(m_i[r] - nm);
            m_i[r] = nm;
            float rs = 0.f;
            #pragma unroll
            for (int nt = 0; nt < 4; nt++) { sacc[nt][r] = __expf(sacc[nt][r] - nm); rs += sacc[nt][r]; }
            #pragma unroll
            for (int o = 1; o < 16; o <<= 1) rs += __shfl_xor(rs, o, 64);
            l_i[r] = l_i[r] * alpha[r] + rs;
        }

        #pragma unroll
        for (int nt = 0; nt < 4; nt++)
            #pragma unroll
            for (int r = 0; r < 4; r++)
                pw[(lg*4 + r)*72 + lr + nt*16] = f2bf(sacc[nt][r]);

        #pragma unroll
        for (int nt = 0; nt < 4; nt++)
            #pragma unroll
            for (int r = 0; r < 4; r++)
                O[nt][r] *= alpha[r];

        asm volatile("s_waitcnt lgkmcnt(0)" ::: "memory");

        #pragma unroll
        for (int kh = 0; kh < 2; kh++) {
            short8 pa = *(const short8*)&pw[lr*72 + kh*32 + lg*8];
            #pragma unroll
            for (int nt = 0; nt < 4; nt++) {
                short8 bv = *(const short8*)&Vt[(lr + nt*16)*72 + kh*32 + lg*8];
                O[nt] = __builtin_amdgcn_mfma_f32_16x16x32_bf16(pa, bv, O[nt], 0, 0, 0);
            }
        }
    }

    #pragma unroll
    for (int r = 0; r < 4; r++) {
        float inv = 1.f / l_i[r];
        #pragma unroll
        for (int nt = 0; nt < 4; nt++)
            pw[(lg*4 + r)*72 + lr + nt*16] = f2bf(O[nt][r] * inv);
    }
    asm volatile("s_waitcnt lgkmcnt(0)" ::: "memory");
    {
        const int row = lane >> 2, c0 = (lane & 3) * 16;
        short8 o0 = *(const short8*)&pw[row*72 + c0];
        short8 o1 = *(const short8*)&pw[row*72 + c0 + 8];
        ushort_t* gp = ctx + headbase + (size_t)(s0 + wave*16 + row) * RS + c0;
        *(short8*)gp       = o0;
        *(short8*)(gp + 8) = o1;
    }
}

extern "C" void kernel_launch(void* const* d_in, const int* in_sizes, int n_in,
                              void* d_out, int out_size, void* d_ws, size_t ws_size,
                              hipStream_t stream)
{
    const float* x    = (const float*)d_in[0];
    const float* wq1  = (const float*)d_in[2];
    const float* bq1  = (const float*)d_in[3];
    const float* wq2  = (const float*)d_in[4];
    const float* bq2  = (const float*)d_in[5];
    const float* wk1  = (const float*)d_in[6];
    const float* bk1  = (const float*)d_in[7];
    const float* wk2  = (const float*)d_in[8];
    const float* bk2  = (const float*)d_in[9];
    const float* wv1  = (const float*)d_in[10];
    const float* bv1  = (const float*)d_in[11];
    const float* wv2  = (const float*)d_in[12];
    const float* bv2  = (const float*)d_in[13];
    const float* wo   = (const float*)d_in[14];
    const float* bo   = (const float*)d_in[15];
    const float* ln1g = (const float*)d_in[16];
    const float* ln1b = (const float*)d_in[17];
    const float* ln2g = (const float*)d_in[18];
    const float* ln2b = (const float*)d_in[19];
    const float* gw   = (const float*)d_in[20];
    const float* gb   = (const float*)d_in[21];
    const float* ew1  = (const float*)d_in[22];
    const float* eb1  = (const float*)d_in[23];
    const float* ew2  = (const float*)d_in[24];
    const float* eb2  = (const float*)d_in[25];
    const float* ew3  = (const float*)d_in[26];
    const float* eb3  = (const float*)d_in[27];
    float* out = (float*)d_out;

    const size_t MB = 1024ull * 1024ull;
    char* w = (char*)d_ws;
    // ---- phase-1 arena [0, 54 MB): attention weights + activations ----
    ushort_t* wq1t = (ushort_t*)(w +  0*MB);
    ushort_t* wq2t = (ushort_t*)(w +  2*MB);
    ushort_t* wk1t = (ushort_t*)(w +  4*MB);
    ushort_t* wk2t = (ushort_t*)(w +  6*MB);
    ushort_t* wv1t = (ushort_t*)(w +  8*MB);
    ushort_t* wv2t = (ushort_t*)(w + 10*MB);
    ushort_t* wot  = (ushort_t*)(w + 12*MB);
    ushort_t* x2h  = (ushort_t*)(w + 14*MB);
    ushort_t* qh   = (ushort_t*)(w + 22*MB);
    ushort_t* kh   = (ushort_t*)(w + 30*MB);
    ushort_t* vh   = (ushort_t*)(w + 38*MB);
    ushort_t* ctxh = (ushort_t*)(w + 46*MB);
    // ---- phase-2 overlays (written only after phase-1 consumers done) ----
    ushort_t* e1t  = (ushort_t*)(w +  0*MB);   // [E][F][D] bf16, 32 MB (up)
    ushort_t* e3t  = (ushort_t*)(w + 32*MB);   // [E][F][D] bf16, 32 MB (up)
    ushort_t* e2t  = (ushort_t*)(w +  0*MB);   // [E][D][F] bf16, 32 MB (down; reuses e1t)
    // ---- persistent MoE state [64 MB, ~105.3 MB) ----
    ushort_t* x2bh = (ushort_t*)(w + 64*MB);   // 8 MB
    ushort_t* hAh  = (ushort_t*)(w + 72*MB);   // flat-compact [2*NTOK+128][F], ~32.5 MB
    char* tail = w + 105*MB;
    int*    cnts = (int*)tail;     tail += 256;
    int*    offs = (int*)tail;     tail += 256;
    int*    idxl = (int*)tail;     tail += (size_t)E_ * NTOK * 4;
    float*  wgtl = (float*)tail;   tail += (size_t)E_ * NTOK * 4;
    int*    tope = (int*)tail;     tail += (size_t)NTOK * 4;
    float2* topw = (float2*)tail;  tail += (size_t)NTOK * 8;

    dim3 blk(256);

    W7 p7;
    p7.s[0]=wq1; p7.d[0]=wq1t; p7.s[1]=wq2; p7.d[1]=wq2t;
    p7.s[2]=wk1; p7.d[2]=wk1t; p7.s[3]=wk2; p7.d[3]=wk2t;
    p7.s[4]=wv1; p7.d[4]=wv1t; p7.s[5]=wv2; p7.d[5]=wv2t;
    p7.s[6]=wo;  p7.d[6]=wot;
    transpose7<<<dim3(32,32,7), blk, 0, stream>>>(p7, D_, D_);

    // --- pre-norm attention ---
    ln_kernel<<<NTOK, blk, 0, stream>>>(x, ln1g, ln1b, x2h);
    QKV qp;
    qp.B1[0]=wq1t; qp.B2[0]=wq2t; qp.bias1[0]=bq1; qp.bias2[0]=bq2; qp.C[0]=qh;
    qp.B1[1]=wk1t; qp.B2[1]=wk2t; qp.bias1[1]=bk1; qp.bias2[1]=bk2; qp.C[1]=kh;
    qp.B1[2]=wv1t; qp.B2[2]=wv2t; qp.bias1[2]=bv1; qp.bias2[2]=bv2; qp.C[2]=vh;
    mgemm_qkv<<<dim3(D_/128, NTOK/128, 3), blk, 0, stream>>>(x2h, qp);
    fattn_kernel<<<B_ * H_ * (S_/64), blk, 0, stream>>>(qh, kh, vh, ctxh);
    mgemm_res<<<dim3(D_/128, NTOK/128), blk, 0, stream>>>(ctxh, wot, bo, x, out,
                                                          NTOK, D_, D_);

    // --- pre-norm MoE SwiGLU FFN (top-2 sparse), gate fused into LN ---
    ln_gate_kernel<<<NTOK, blk, 0, stream>>>(out, ln2g, ln2b, x2bh, gw, gb,
                                             tope, topw);
    build_lists<<<dim3(E_), blk, 0, stream>>>(tope, topw, cnts, offs, idxl, wgtl);
    // phase-1 buffers are dead from here; overlay expert weights.
    transpose_e13<<<dim3(F_/32, D_/32, 2*E_), blk, 0, stream>>>(ew1, ew3, e1t, e3t);
    mgemm_up_all<<<dim3(F_/128, NTOK/128, E_), blk, 0, stream>>>(
        x2bh, idxl, cnts, offs, e1t, eb1, e3t, eb3, hAh);
    transpose_e2<<<dim3(D_/32, F_/32, E_), blk, 0, stream>>>(ew2, e2t);
    mgemm_down_all<<<dim3(D_/128, NTOK/128, E_), blk, 0, stream>>>(
        hAh, idxl, wgtl, cnts, offs, e2t, eb2, out);
}